// Round 2
// baseline (4166.963 us; speedup 1.0000x reference)
//
#include <hip/hip_runtime.h>
#include <math.h>

#define HIDN 1024
#define NHEADS 16
#define DHEAD 64
#define FFD 4096
#define LN_EPS 1e-6f
#define NEGV -1e9f

// ---------------------------------------------------------------------------
// GEMM: C[M,N] = A[M,K] * W[N,K]^T + bias[N], optional ReLU.
// BM=128, BN=64, BK=16, 256 threads, 8x4 micro-tile.
// LDS tiles stored k-major (As[k][m], Ws[k][n]) so compute reads are b128.
// ---------------------------------------------------------------------------
template<int RELU>
__global__ __launch_bounds__(256)
void gemm_nt(const float* __restrict__ A, const float* __restrict__ W,
             const float* __restrict__ bias, float* __restrict__ C,
             int M, int N, int K)
{
    __shared__ float As[16][132];   // pad 132: stride%16B==0, 2-way banks max
    __shared__ float Ws[16][68];

    const int tid = threadIdx.x;
    const int tx  = tid & 15;       // -> N
    const int ty  = tid >> 4;       // -> M
    const int m0  = blockIdx.x * 128;
    const int n0  = blockIdx.y * 64;

    // staging indices
    const int ar = tid >> 1;            // 0..127
    const int ak = (tid & 1) * 8;       // 0 or 8
    const int wr = tid >> 2;            // 0..63
    const int wk = (tid & 3) * 4;       // 0,4,8,12

    const float* Ap = A + (size_t)(m0 + ar) * K + ak;
    const float* Wp = W + (size_t)(n0 + wr) * K + wk;

    float acc[8][4];
    #pragma unroll
    for (int i = 0; i < 8; ++i)
        #pragma unroll
        for (int j = 0; j < 4; ++j) acc[i][j] = 0.f;

    for (int k0 = 0; k0 < K; k0 += 16) {
        float4 a0 = *(const float4*)(Ap + k0);
        float4 a1 = *(const float4*)(Ap + k0 + 4);
        float4 wv = *(const float4*)(Wp + k0);
        __syncthreads();
        As[ak+0][ar] = a0.x; As[ak+1][ar] = a0.y;
        As[ak+2][ar] = a0.z; As[ak+3][ar] = a0.w;
        As[ak+4][ar] = a1.x; As[ak+5][ar] = a1.y;
        As[ak+6][ar] = a1.z; As[ak+7][ar] = a1.w;
        Ws[wk+0][wr] = wv.x; Ws[wk+1][wr] = wv.y;
        Ws[wk+2][wr] = wv.z; Ws[wk+3][wr] = wv.w;
        __syncthreads();
        #pragma unroll
        for (int kk = 0; kk < 16; ++kk) {
            float4 av0 = *(const float4*)&As[kk][ty*8];
            float4 av1 = *(const float4*)&As[kk][ty*8+4];
            float4 bv  = *(const float4*)&Ws[kk][tx*4];
            float am[8] = {av0.x,av0.y,av0.z,av0.w, av1.x,av1.y,av1.z,av1.w};
            float bm[4] = {bv.x,bv.y,bv.z,bv.w};
            #pragma unroll
            for (int i = 0; i < 8; ++i)
                #pragma unroll
                for (int j = 0; j < 4; ++j)
                    acc[i][j] = fmaf(am[i], bm[j], acc[i][j]);
        }
    }

    float4 bvec = *(const float4*)(bias + n0 + tx*4);
    float bb[4] = {bvec.x, bvec.y, bvec.z, bvec.w};
    #pragma unroll
    for (int i = 0; i < 8; ++i) {
        float4 o;
        o.x = acc[i][0] + bb[0];
        o.y = acc[i][1] + bb[1];
        o.z = acc[i][2] + bb[2];
        o.w = acc[i][3] + bb[3];
        if (RELU) {
            o.x = fmaxf(o.x, 0.f); o.y = fmaxf(o.y, 0.f);
            o.z = fmaxf(o.z, 0.f); o.w = fmaxf(o.w, 0.f);
        }
        *(float4*)(C + (size_t)(m0 + ty*8 + i) * N + n0 + tx*4) = o;
    }
}

// ---------------------------------------------------------------------------
// Fused attention, one block per (b, head, 64-row q tile), online softmax
// over 64-wide K/V tiles. Q/K staged d-major, V/P k-major. 4x4 micro-tiles.
// Q,K,V are [B, L, 1024] with head h occupying cols [h*64, h*64+64).
// mask: int[B, Lk], score replaced by NEGV where mask==1.
// Staging: 64x64 tile = 4096 floats = 256 threads x 4 float4 each.
// ---------------------------------------------------------------------------
template<int HAS_MASK>
__global__ __launch_bounds__(256)
void attn_fused(const float* __restrict__ Q, const float* __restrict__ K,
                const float* __restrict__ V, const int* __restrict__ mask,
                float* __restrict__ O, int Lk)
{
    __shared__ float Qs[64][68];   // [d][q]
    __shared__ float Ks[64][68];   // [d][k]
    __shared__ float Vs[64][68];   // [k][d]
    __shared__ float Ps[64][68];   // [k][q]
    __shared__ int   smask[64];

    const int tid = threadIdx.x;
    const int tx  = tid & 15;
    const int ty  = tid >> 4;
    const int q0  = blockIdx.x * 64;
    const int h   = blockIdx.y;
    const int b   = blockIdx.z;
    const int Lq  = 512;

    const int sr = tid >> 2;            // 0..63: tile row
    const int sc = (tid & 3) * 16;      // 0,16,32,48: col base (4 float4 each)

    // stage Q tile -> [d][q]  (full 64x64)
    {
        const float* qp = Q + (size_t)(b*Lq + q0 + sr) * HIDN + h*DHEAD + sc;
        #pragma unroll
        for (int t = 0; t < 4; ++t) {
            float4 v = *(const float4*)(qp + t*4);
            Qs[sc+t*4+0][sr] = v.x; Qs[sc+t*4+1][sr] = v.y;
            Qs[sc+t*4+2][sr] = v.z; Qs[sc+t*4+3][sr] = v.w;
        }
    }

    float mrun[4], lrun[4], Oc[4][4];
    #pragma unroll
    for (int i = 0; i < 4; ++i) {
        mrun[i] = -INFINITY; lrun[i] = 0.f;
        #pragma unroll
        for (int j = 0; j < 4; ++j) Oc[i][j] = 0.f;
    }

    for (int k0 = 0; k0 < Lk; k0 += 64) {
        // stage K (d-major), V (k-major), mask — full 64x64 tiles
        {
            const float* kp = K + (size_t)(b*Lk + k0 + sr) * HIDN + h*DHEAD + sc;
            #pragma unroll
            for (int t = 0; t < 4; ++t) {
                float4 v = *(const float4*)(kp + t*4);
                Ks[sc+t*4+0][sr] = v.x; Ks[sc+t*4+1][sr] = v.y;
                Ks[sc+t*4+2][sr] = v.z; Ks[sc+t*4+3][sr] = v.w;
            }
            const float* vp = V + (size_t)(b*Lk + k0 + sr) * HIDN + h*DHEAD + sc;
            #pragma unroll
            for (int t = 0; t < 4; ++t)
                *(float4*)&Vs[sr][sc + t*4] = *(const float4*)(vp + t*4);
            if (HAS_MASK && tid < 64) smask[tid] = mask[b*Lk + k0 + tid];
        }
        __syncthreads();

        // S = (Q K^T) / 8, then mask
        float s[4][4];
        #pragma unroll
        for (int i = 0; i < 4; ++i)
            #pragma unroll
            for (int j = 0; j < 4; ++j) s[i][j] = 0.f;
        for (int d = 0; d < 64; ++d) {
            float4 qa = *(const float4*)&Qs[d][ty*4];
            float4 kb = *(const float4*)&Ks[d][tx*4];
            float am[4] = {qa.x,qa.y,qa.z,qa.w};
            float bm[4] = {kb.x,kb.y,kb.z,kb.w};
            #pragma unroll
            for (int i = 0; i < 4; ++i)
                #pragma unroll
                for (int j = 0; j < 4; ++j)
                    s[i][j] = fmaf(am[i], bm[j], s[i][j]);
        }
        #pragma unroll
        for (int i = 0; i < 4; ++i)
            #pragma unroll
            for (int j = 0; j < 4; ++j) {
                float sv = s[i][j] * 0.125f;
                if (HAS_MASK && smask[tx*4+j]) sv = NEGV;
                s[i][j] = sv;
            }

        // online softmax update (rows are per-i, reduce over the 16 tx lanes)
        #pragma unroll
        for (int i = 0; i < 4; ++i) {
            float tm = fmaxf(fmaxf(s[i][0], s[i][1]), fmaxf(s[i][2], s[i][3]));
            #pragma unroll
            for (int m = 1; m < 16; m <<= 1) tm = fmaxf(tm, __shfl_xor(tm, m));
            float mnew = fmaxf(mrun[i], tm);
            float f = __expf(mrun[i] - mnew);
            float ps = 0.f;
            #pragma unroll
            for (int j = 0; j < 4; ++j) {
                float p = __expf(s[i][j] - mnew);
                s[i][j] = p;
                ps += p;
            }
            #pragma unroll
            for (int m = 1; m < 16; m <<= 1) ps += __shfl_xor(ps, m);
            lrun[i] = lrun[i] * f + ps;
            mrun[i] = mnew;
            #pragma unroll
            for (int j = 0; j < 4; ++j) Oc[i][j] *= f;
            #pragma unroll
            for (int j = 0; j < 4; ++j) Ps[tx*4+j][ty*4+i] = s[i][j];
        }
        __syncthreads();

        // O += P V
        for (int k = 0; k < 64; ++k) {
            float4 pa = *(const float4*)&Ps[k][ty*4];
            float4 vb = *(const float4*)&Vs[k][tx*4];
            float am[4] = {pa.x,pa.y,pa.z,pa.w};
            float bm[4] = {vb.x,vb.y,vb.z,vb.w};
            #pragma unroll
            for (int i = 0; i < 4; ++i)
                #pragma unroll
                for (int j = 0; j < 4; ++j)
                    Oc[i][j] = fmaf(am[i], bm[j], Oc[i][j]);
        }
        __syncthreads();
    }

    #pragma unroll
    for (int i = 0; i < 4; ++i) {
        float inv = 1.f / lrun[i];
        float4 o;
        o.x = Oc[i][0] * inv; o.y = Oc[i][1] * inv;
        o.z = Oc[i][2] * inv; o.w = Oc[i][3] * inv;
        *(float4*)(O + (size_t)(b*Lq + q0 + ty*4 + i) * HIDN + h*DHEAD + tx*4) = o;
    }
}

// ---------------------------------------------------------------------------
// LayerNorm(X + R) * g + b, one block per row of 1024.
// ---------------------------------------------------------------------------
__global__ __launch_bounds__(256)
void ln_res(const float* __restrict__ X, const float* __restrict__ R,
            const float* __restrict__ G, const float* __restrict__ Bv,
            float* __restrict__ Out)
{
    const int row = blockIdx.x;
    const int tid = threadIdx.x;
    const size_t base = (size_t)row * HIDN + tid * 4;
    float4 xv = *(const float4*)(X + base);
    float4 rv = *(const float4*)(R + base);
    float y[4] = {xv.x+rv.x, xv.y+rv.y, xv.z+rv.z, xv.w+rv.w};
    float s1 = y[0] + y[1] + y[2] + y[3];
    float s2 = y[0]*y[0] + y[1]*y[1] + y[2]*y[2] + y[3]*y[3];
    #pragma unroll
    for (int m = 1; m < 64; m <<= 1) {
        s1 += __shfl_xor(s1, m);
        s2 += __shfl_xor(s2, m);
    }
    __shared__ float red1[4], red2[4];
    const int wave = tid >> 6, lane = tid & 63;
    if (lane == 0) { red1[wave] = s1; red2[wave] = s2; }
    __syncthreads();
    s1 = red1[0] + red1[1] + red1[2] + red1[3];
    s2 = red2[0] + red2[1] + red2[2] + red2[3];
    const float mean = s1 * (1.f / HIDN);
    const float var  = s2 * (1.f / HIDN) - mean * mean;
    const float inv  = rsqrtf(var + LN_EPS);
    float4 gv = *(const float4*)(G + tid*4);
    float4 bv = *(const float4*)(Bv + tid*4);
    float4 o;
    o.x = gv.x * (y[0]-mean) * inv + bv.x;
    o.y = gv.y * (y[1]-mean) * inv + bv.y;
    o.z = gv.z * (y[2]-mean) * inv + bv.z;
    o.w = gv.w * (y[3]-mean) * inv + bv.w;
    *(float4*)(Out + base) = o;
}

// ---------------------------------------------------------------------------
extern "C" void kernel_launch(void* const* d_in, const int* in_sizes, int n_in,
                              void* d_out, int out_size, void* d_ws, size_t ws_size,
                              hipStream_t stream)
{
    const float* img   = (const float*)d_in[0];
    const float* ques  = (const float*)d_in[1];
    const float* kg    = (const float*)d_in[2];
    const int*   qmask = (const int*)d_in[3];
    const int*   kmask = (const int*)d_in[4];
    const float* qw = (const float*)d_in[5];
    const float* qb = (const float*)d_in[6];
    const float* kw = (const float*)d_in[7];
    const float* kb = (const float*)d_in[8];
    const float* vw = (const float*)d_in[9];
    const float* vb = (const float*)d_in[10];
    const float* ow = (const float*)d_in[11];
    const float* ob = (const float*)d_in[12];
    const float* w1 = (const float*)d_in[13];
    const float* b1 = (const float*)d_in[14];
    const float* w2 = (const float*)d_in[15];
    const float* b2 = (const float*)d_in[16];
    const float* lng = (const float*)d_in[17];
    const float* lnb = (const float*)d_in[18];
    float* out = (float*)d_out;

    const int B = 16;
    const int NX = B * 512;            // 8192 query rows
    const size_t SLOT = (size_t)8192 * 1024;
    const size_t WSTEP = (size_t)1024 * 1024;   // per-block weight stride

    float* ws = (float*)d_ws;
    float* bX = ws;
    float* bQ = ws + 1*SLOT;
    float* bK = ws + 2*SLOT;
    float* bV = ws + 3*SLOT;
    float* bO = ws + 4*SLOT;
    float* bM = ws + 5*SLOT;
    float* bH = bQ;                     // FFN hidden: spans slots 1..4

    dim3 blk(256);
    auto gemm = [&](const float* A, const float* W, const float* bias, float* C,
                    int M, int N, int K, int relu) {
        dim3 grid(M / 128, N / 64);
        if (relu) gemm_nt<1><<<grid, blk, 0, stream>>>(A, W, bias, C, M, N, K);
        else      gemm_nt<0><<<grid, blk, 0, stream>>>(A, W, bias, C, M, N, K);
    };

    // ---- block 0: self-attention on img_feat (no mask, Lk=512) ----
    gemm(img, qw + 0*WSTEP, qb + 0*1024, bQ, NX,   1024, 1024, 0);
    gemm(img, kw + 0*WSTEP, kb + 0*1024, bK, NX,   1024, 1024, 0);
    gemm(img, vw + 0*WSTEP, vb + 0*1024, bV, NX,   1024, 1024, 0);
    attn_fused<0><<<dim3(8, NHEADS, B), blk, 0, stream>>>(bQ, bK, bV, nullptr, bO, 512);
    gemm(bO, ow + 0*WSTEP, ob + 0*1024, bM, NX, 1024, 1024, 0);
    ln_res<<<NX, blk, 0, stream>>>(img, bM, lng + 0*1024, lnb + 0*1024, bX);

    // ---- block 1: cross-attention to ques (Lk=64, mask) ----
    gemm(bX,   qw + 1*WSTEP, qb + 1*1024, bQ, NX,     1024, 1024, 0);
    gemm(ques, kw + 1*WSTEP, kb + 1*1024, bK, B*64,   1024, 1024, 0);
    gemm(ques, vw + 1*WSTEP, vb + 1*1024, bV, B*64,   1024, 1024, 0);
    attn_fused<1><<<dim3(8, NHEADS, B), blk, 0, stream>>>(bQ, bK, bV, qmask, bO, 64);
    gemm(bO, ow + 1*WSTEP, ob + 1*1024, bM, NX, 1024, 1024, 0);
    ln_res<<<NX, blk, 0, stream>>>(bX, bM, lng + 1*1024, lnb + 1*1024, bX);

    // ---- block 2: cross-attention to kg (Lk=128, mask) ----
    gemm(bX, qw + 2*WSTEP, qb + 2*1024, bQ, NX,     1024, 1024, 0);
    gemm(kg, kw + 2*WSTEP, kb + 2*1024, bK, B*128,  1024, 1024, 0);
    gemm(kg, vw + 2*WSTEP, vb + 2*1024, bV, B*128,  1024, 1024, 0);
    attn_fused<1><<<dim3(8, NHEADS, B), blk, 0, stream>>>(bQ, bK, bV, kmask, bO, 128);
    gemm(bO, ow + 2*WSTEP, ob + 2*1024, bM, NX, 1024, 1024, 0);
    ln_res<<<NX, blk, 0, stream>>>(bX, bM, lng + 2*1024, lnb + 2*1024, bX);

    // ---- FFN ----
    gemm(bX, w1, b1, bH, NX, FFD,  1024, 1);   // ReLU fused
    gemm(bH, w2, b2, bM, NX, 1024, FFD,  0);
    ln_res<<<NX, blk, 0, stream>>>(bX, bM, lng + 3*1024, lnb + 3*1024, out);
}

// Round 3
// 1033.428 us; speedup vs baseline: 4.0322x; 4.0322x over previous
//
#include <hip/hip_runtime.h>
#include <math.h>

#define HIDN 1024
#define NHEADS 16
#define DHEAD 64
#define FFD 4096
#define LN_EPS 1e-6f
#define NEGV -1e9f

typedef __bf16 bf16_t;
typedef __bf16 bf16x8 __attribute__((ext_vector_type(8)));
typedef float f32x4 __attribute__((ext_vector_type(4)));
typedef unsigned short ushort8 __attribute__((ext_vector_type(8)));
typedef unsigned short ushort4v __attribute__((ext_vector_type(4)));

__device__ __forceinline__ unsigned short f2bf(float f) {
    unsigned u = __float_as_uint(f);
    return (unsigned short)((u + 0x7FFFu + ((u >> 16) & 1u)) >> 16);
}
__device__ __forceinline__ float bf2f(unsigned short u) {
    return __uint_as_float((unsigned)u << 16);
}
__device__ __forceinline__ void gld16(const void* g, void* l) {
    __builtin_amdgcn_global_load_lds(
        (const __attribute__((address_space(1))) void*)g,
        (__attribute__((address_space(3))) void*)l, 16, 0, 0);
}

// ---------------------------------------------------------------------------
// bf16 MFMA GEMM: C[M,N] = A[M,K] * W[N,K]^T + bias[N].
// BM=BN=128, BK=64, 256 threads = 4 waves in 2x2, each wave 64x64 out
// (4x4 frags of 16x16x32). global_load_lds width-16 staging, single-buffer.
// Output fp32 (Cf) or bf16 (Cb) per OUT_BF16; optional fused ReLU.
// ---------------------------------------------------------------------------
template<int OUT_BF16, int RELU>
__global__ __launch_bounds__(256)
void gemm_mfma(const bf16_t* __restrict__ A, const bf16_t* __restrict__ W,
               const float* __restrict__ bias, float* __restrict__ Cf,
               unsigned short* __restrict__ Cb, int M, int N, int K)
{
    __shared__ __align__(16) bf16_t As[128 * 64];
    __shared__ __align__(16) bf16_t Bs[128 * 64];

    const int tid  = threadIdx.x;
    const int wid  = tid >> 6;
    const int lane = tid & 63;
    const int m0 = blockIdx.x * 128;
    const int n0 = blockIdx.y * 128;
    const int wm = (wid & 1) * 64;   // wave row offset in tile
    const int wn = (wid >> 1) * 64;  // wave col offset in tile

    // staging: per call c (0..3), wave stages 8 rows (1 KiB). lane covers
    // row (lane>>3), 16B chunk (lane&7) -> matches HW lane*16B linear dest.
    const int sr = (wid << 3) + (lane >> 3);   // 0..31
    const int sk = (lane & 7) * 8;             // k elem offset
    const bf16_t* pa = A + (size_t)(m0 + sr) * K + sk;
    const bf16_t* pb = W + (size_t)(n0 + sr) * K + sk;
    bf16_t* lA = &As[(wid << 3) * 64];
    bf16_t* lB = &Bs[(wid << 3) * 64];

    // fragment read bases
    const int lr = lane & 15;
    const int lk = (lane >> 4) * 8;
    const bf16_t* fa = &As[(wm + lr) * 64 + lk];
    const bf16_t* fb = &Bs[(wn + lr) * 64 + lk];

    f32x4 acc[4][4];
    #pragma unroll
    for (int i = 0; i < 4; ++i)
        #pragma unroll
        for (int j = 0; j < 4; ++j) acc[i][j] = (f32x4){0.f, 0.f, 0.f, 0.f};

    for (int k0 = 0; k0 < K; k0 += 64) {
        __syncthreads();
        #pragma unroll
        for (int c = 0; c < 4; ++c) {
            gld16(pa + (size_t)c * 32 * K + k0, lA + c * 32 * 64);
            gld16(pb + (size_t)c * 32 * K + k0, lB + c * 32 * 64);
        }
        asm volatile("s_waitcnt vmcnt(0)" ::: "memory");
        __syncthreads();
        #pragma unroll
        for (int kk = 0; kk < 64; kk += 32) {
            bf16x8 a[4], b[4];
            #pragma unroll
            for (int i = 0; i < 4; ++i) {
                a[i] = *(const bf16x8*)(fa + i * 16 * 64 + kk);
                b[i] = *(const bf16x8*)(fb + i * 16 * 64 + kk);
            }
            #pragma unroll
            for (int i = 0; i < 4; ++i)
                #pragma unroll
                for (int j = 0; j < 4; ++j)
                    acc[i][j] = __builtin_amdgcn_mfma_f32_16x16x32_bf16(
                        a[i], b[j], acc[i][j], 0, 0, 0);
        }
    }

    // epilogue: C row = m0+wm+i*16+(lane>>4)*4+r, col = n0+wn+j*16+(lane&15)
    const int er = wm + (lane >> 4) * 4;
    const int ec = wn + (lane & 15);
    float bv[4];
    #pragma unroll
    for (int j = 0; j < 4; ++j) bv[j] = bias[n0 + ec + j * 16];
    #pragma unroll
    for (int i = 0; i < 4; ++i)
        #pragma unroll
        for (int j = 0; j < 4; ++j)
            #pragma unroll
            for (int r = 0; r < 4; ++r) {
                float v = acc[i][j][r] + bv[j];
                if (RELU) v = fmaxf(v, 0.f);
                size_t idx = (size_t)(m0 + er + i * 16 + r) * N + (n0 + ec + j * 16);
                if (OUT_BF16) Cb[idx] = f2bf(v);
                else          Cf[idx] = v;
            }
}

// ---------------------------------------------------------------------------
// Fused attention (fp32 core, bf16 Q/K/V in, bf16 O out).
// One block per (b, head, 64-row q tile), online softmax over 64-wide tiles.
// ---------------------------------------------------------------------------
template<int HAS_MASK>
__global__ __launch_bounds__(256)
void attn_fused(const unsigned short* __restrict__ Q,
                const unsigned short* __restrict__ K,
                const unsigned short* __restrict__ V,
                const int* __restrict__ mask,
                unsigned short* __restrict__ O, int Lk)
{
    __shared__ float Qs[64][68];   // [d][q]
    __shared__ float Ks[64][68];   // [d][k]
    __shared__ float Vs[64][68];   // [k][d]
    __shared__ float Ps[64][68];   // [k][q]
    __shared__ int   smask[64];

    const int tid = threadIdx.x;
    const int tx  = tid & 15;
    const int ty  = tid >> 4;
    const int q0  = blockIdx.x * 64;
    const int h   = blockIdx.y;
    const int b   = blockIdx.z;
    const int Lq  = 512;

    const int sr = tid >> 2;            // tile row 0..63
    const int sc = (tid & 3) * 16;      // 16 elems per thread

    {
        const unsigned short* qp = Q + (size_t)(b*Lq + q0 + sr) * HIDN + h*DHEAD + sc;
        ushort8 u0 = *(const ushort8*)qp;
        ushort8 u1 = *(const ushort8*)(qp + 8);
        #pragma unroll
        for (int t = 0; t < 8; ++t) {
            Qs[sc + t][sr]     = bf2f(u0[t]);
            Qs[sc + 8 + t][sr] = bf2f(u1[t]);
        }
    }

    float mrun[4], lrun[4], Oc[4][4];
    #pragma unroll
    for (int i = 0; i < 4; ++i) {
        mrun[i] = -INFINITY; lrun[i] = 0.f;
        #pragma unroll
        for (int j = 0; j < 4; ++j) Oc[i][j] = 0.f;
    }

    for (int k0 = 0; k0 < Lk; k0 += 64) {
        {
            const unsigned short* kp = K + (size_t)(b*Lk + k0 + sr) * HIDN + h*DHEAD + sc;
            ushort8 u0 = *(const ushort8*)kp;
            ushort8 u1 = *(const ushort8*)(kp + 8);
            #pragma unroll
            for (int t = 0; t < 8; ++t) {
                Ks[sc + t][sr]     = bf2f(u0[t]);
                Ks[sc + 8 + t][sr] = bf2f(u1[t]);
            }
            const unsigned short* vp = V + (size_t)(b*Lk + k0 + sr) * HIDN + h*DHEAD + sc;
            ushort8 v0 = *(const ushort8*)vp;
            ushort8 v1 = *(const ushort8*)(vp + 8);
            #pragma unroll
            for (int t = 0; t < 8; ++t) {
                Vs[sr][sc + t]     = bf2f(v0[t]);
                Vs[sr][sc + 8 + t] = bf2f(v1[t]);
            }
            if (HAS_MASK && tid < 64) smask[tid] = mask[b*Lk + k0 + tid];
        }
        __syncthreads();

        float s[4][4];
        #pragma unroll
        for (int i = 0; i < 4; ++i)
            #pragma unroll
            for (int j = 0; j < 4; ++j) s[i][j] = 0.f;
        for (int d = 0; d < 64; ++d) {
            float4 qa = *(const float4*)&Qs[d][ty*4];
            float4 kb = *(const float4*)&Ks[d][tx*4];
            float am[4] = {qa.x,qa.y,qa.z,qa.w};
            float bm[4] = {kb.x,kb.y,kb.z,kb.w};
            #pragma unroll
            for (int i = 0; i < 4; ++i)
                #pragma unroll
                for (int j = 0; j < 4; ++j)
                    s[i][j] = fmaf(am[i], bm[j], s[i][j]);
        }
        #pragma unroll
        for (int i = 0; i < 4; ++i)
            #pragma unroll
            for (int j = 0; j < 4; ++j) {
                float sv = s[i][j] * 0.125f;
                if (HAS_MASK && smask[tx*4+j]) sv = NEGV;
                s[i][j] = sv;
            }

        #pragma unroll
        for (int i = 0; i < 4; ++i) {
            float tm = fmaxf(fmaxf(s[i][0], s[i][1]), fmaxf(s[i][2], s[i][3]));
            #pragma unroll
            for (int m = 1; m < 16; m <<= 1) tm = fmaxf(tm, __shfl_xor(tm, m));
            float mnew = fmaxf(mrun[i], tm);
            float f = __expf(mrun[i] - mnew);
            float ps = 0.f;
            #pragma unroll
            for (int j = 0; j < 4; ++j) {
                float p = __expf(s[i][j] - mnew);
                s[i][j] = p;
                ps += p;
            }
            #pragma unroll
            for (int m = 1; m < 16; m <<= 1) ps += __shfl_xor(ps, m);
            lrun[i] = lrun[i] * f + ps;
            mrun[i] = mnew;
            #pragma unroll
            for (int j = 0; j < 4; ++j) Oc[i][j] *= f;
            #pragma unroll
            for (int j = 0; j < 4; ++j) Ps[tx*4+j][ty*4+i] = s[i][j];
        }
        __syncthreads();

        for (int k = 0; k < 64; ++k) {
            float4 pa = *(const float4*)&Ps[k][ty*4];
            float4 vb = *(const float4*)&Vs[k][tx*4];
            float am[4] = {pa.x,pa.y,pa.z,pa.w};
            float bm[4] = {vb.x,vb.y,vb.z,vb.w};
            #pragma unroll
            for (int i = 0; i < 4; ++i)
                #pragma unroll
                for (int j = 0; j < 4; ++j)
                    Oc[i][j] = fmaf(am[i], bm[j], Oc[i][j]);
        }
        __syncthreads();
    }

    #pragma unroll
    for (int i = 0; i < 4; ++i) {
        float inv = 1.f / lrun[i];
        ushort4v o;
        o[0] = f2bf(Oc[i][0] * inv); o[1] = f2bf(Oc[i][1] * inv);
        o[2] = f2bf(Oc[i][2] * inv); o[3] = f2bf(Oc[i][3] * inv);
        *(ushort4v*)(O + (size_t)(b*Lq + q0 + ty*4 + i) * HIDN + h*DHEAD + tx*4) = o;
    }
}

// ---------------------------------------------------------------------------
// LayerNorm(X + R) * g + b; fp32 out, optional bf16 twin for next GEMM.
// ---------------------------------------------------------------------------
template<int DUAL>
__global__ __launch_bounds__(256)
void ln_res(const float* __restrict__ X, const float* __restrict__ R,
            const float* __restrict__ G, const float* __restrict__ Bv,
            float* __restrict__ Out, unsigned short* __restrict__ OutB)
{
    const int row = blockIdx.x;
    const int tid = threadIdx.x;
    const size_t base = (size_t)row * HIDN + tid * 4;
    float4 xv = *(const float4*)(X + base);
    float4 rv = *(const float4*)(R + base);
    float y[4] = {xv.x+rv.x, xv.y+rv.y, xv.z+rv.z, xv.w+rv.w};
    float s1 = y[0] + y[1] + y[2] + y[3];
    float s2 = y[0]*y[0] + y[1]*y[1] + y[2]*y[2] + y[3]*y[3];
    #pragma unroll
    for (int m = 1; m < 64; m <<= 1) {
        s1 += __shfl_xor(s1, m);
        s2 += __shfl_xor(s2, m);
    }
    __shared__ float red1[4], red2[4];
    const int wave = tid >> 6, lane = tid & 63;
    if (lane == 0) { red1[wave] = s1; red2[wave] = s2; }
    __syncthreads();
    s1 = red1[0] + red1[1] + red1[2] + red1[3];
    s2 = red2[0] + red2[1] + red2[2] + red2[3];
    const float mean = s1 * (1.f / HIDN);
    const float var  = s2 * (1.f / HIDN) - mean * mean;
    const float inv  = rsqrtf(var + LN_EPS);
    float4 gv = *(const float4*)(G + tid*4);
    float4 bv = *(const float4*)(Bv + tid*4);
    float4 o;
    o.x = gv.x * (y[0]-mean) * inv + bv.x;
    o.y = gv.y * (y[1]-mean) * inv + bv.y;
    o.z = gv.z * (y[2]-mean) * inv + bv.z;
    o.w = gv.w * (y[3]-mean) * inv + bv.w;
    *(float4*)(Out + base) = o;
    if (DUAL) {
        ushort4v ob;
        ob[0] = f2bf(o.x); ob[1] = f2bf(o.y); ob[2] = f2bf(o.z); ob[3] = f2bf(o.w);
        *(ushort4v*)(OutB + base) = ob;
    }
}

// ---------------------------------------------------------------------------
// fp32 -> bf16 bulk convert (8 elems / thread / step).
// ---------------------------------------------------------------------------
__global__ __launch_bounds__(256)
void cvt_bf16(const float* __restrict__ in, unsigned short* __restrict__ out, int n8)
{
    int i = blockIdx.x * blockDim.x + threadIdx.x;
    const int stride = gridDim.x * blockDim.x;
    for (; i < n8; i += stride) {
        const float4* p = (const float4*)in + (size_t)i * 2;
        float4 a = p[0], b = p[1];
        ushort8 o;
        o[0] = f2bf(a.x); o[1] = f2bf(a.y); o[2] = f2bf(a.z); o[3] = f2bf(a.w);
        o[4] = f2bf(b.x); o[5] = f2bf(b.y); o[6] = f2bf(b.z); o[7] = f2bf(b.w);
        ((ushort8*)out)[i] = o;
    }
}

// ---------------------------------------------------------------------------
extern "C" void kernel_launch(void* const* d_in, const int* in_sizes, int n_in,
                              void* d_out, int out_size, void* d_ws, size_t ws_size,
                              hipStream_t stream)
{
    const float* img   = (const float*)d_in[0];
    const float* ques  = (const float*)d_in[1];
    const float* kg    = (const float*)d_in[2];
    const int*   qmask = (const int*)d_in[3];
    const int*   kmask = (const int*)d_in[4];
    const float* qw = (const float*)d_in[5];
    const float* qb = (const float*)d_in[6];
    const float* kw = (const float*)d_in[7];
    const float* kb = (const float*)d_in[8];
    const float* vw = (const float*)d_in[9];
    const float* vb = (const float*)d_in[10];
    const float* ow = (const float*)d_in[11];
    const float* ob = (const float*)d_in[12];
    const float* w1 = (const float*)d_in[13];
    const float* b1 = (const float*)d_in[14];
    const float* w2 = (const float*)d_in[15];
    const float* b2 = (const float*)d_in[16];
    const float* lng = (const float*)d_in[17];
    const float* lnb = (const float*)d_in[18];
    float* out = (float*)d_out;

    const int B = 16;
    const int NX = B * 512;                    // 8192 rows
    const size_t WSTEP = (size_t)1024 * 1024;  // per-block weight stride
    const size_t MB = (size_t)1 << 20;

    char* wsb = (char*)d_ws;
    float*          bX    = (float*)(wsb);                 // 32 MB fp32
    float*          bM    = (float*)(wsb + 32*MB);         // 32 MB fp32
    unsigned short* bQ    = (unsigned short*)(wsb + 64*MB);   // 16 MB bf16
    unsigned short* bK    = (unsigned short*)(wsb + 80*MB);   // 16 MB
    unsigned short* bV    = (unsigned short*)(wsb + 96*MB);   // 16 MB
    unsigned short* bOb   = (unsigned short*)(wsb + 112*MB);  // 16 MB
    unsigned short* xb    = (unsigned short*)(wsb + 128*MB);  // 16 MB
    unsigned short* quesb = (unsigned short*)(wsb + 144*MB);  // 2 MB
    unsigned short* kgb   = (unsigned short*)(wsb + 146*MB);  // 4 MB
    unsigned short* wb    = (unsigned short*)(wsb + 152*MB);  // 8 MB staging
    unsigned short* hb    = (unsigned short*)(wsb + 64*MB);   // 64 MB, overlays bQ..bOb (dead in FFN)

    dim3 blk(256);
    auto cvt = [&](const float* src, unsigned short* dst, size_t n) {
        int n8 = (int)(n / 8);
        int grid = (n8 + 255) / 256; if (grid > 2048) grid = 2048;
        cvt_bf16<<<grid, blk, 0, stream>>>(src, dst, n8);
    };
    auto gemm = [&](const unsigned short* A, const float* Wsrc, size_t welems,
                    const float* bias, float* Cf, unsigned short* Cb,
                    int M, int N, int K, int relu) {
        cvt(Wsrc, wb, welems);
        dim3 grid(M / 128, N / 128);
        const bf16_t* Ab = (const bf16_t*)A;
        const bf16_t* Wb = (const bf16_t*)wb;
        if (Cb) {
            if (relu) gemm_mfma<1,1><<<grid, blk, 0, stream>>>(Ab, Wb, bias, nullptr, Cb, M, N, K);
            else      gemm_mfma<1,0><<<grid, blk, 0, stream>>>(Ab, Wb, bias, nullptr, Cb, M, N, K);
        } else {
            gemm_mfma<0,0><<<grid, blk, 0, stream>>>(Ab, Wb, bias, Cf, nullptr, M, N, K);
        }
    };

    // activation conversions
    cvt(img,  xb,    (size_t)NX * HIDN);
    cvt(ques, quesb, (size_t)B * 64 * HIDN);
    cvt(kg,   kgb,   (size_t)B * 128 * HIDN);

    const unsigned short* Akv[3] = {xb, quesb, kgb};
    const int Mkv[3] = {NX, B * 64, B * 128};
    const int Lk[3]  = {512, 64, 128};

    for (int t = 0; t < 3; ++t) {
        gemm(xb,      qw + t*WSTEP, WSTEP, qb + t*1024, nullptr, bQ, NX,     1024, 1024, 0);
        gemm(Akv[t],  kw + t*WSTEP, WSTEP, kb + t*1024, nullptr, bK, Mkv[t], 1024, 1024, 0);
        gemm(Akv[t],  vw + t*WSTEP, WSTEP, vb + t*1024, nullptr, bV, Mkv[t], 1024, 1024, 0);
        if (t == 0)
            attn_fused<0><<<dim3(8, NHEADS, B), blk, 0, stream>>>(bQ, bK, bV, nullptr, bOb, Lk[t]);
        else
            attn_fused<1><<<dim3(8, NHEADS, B), blk, 0, stream>>>(bQ, bK, bV,
                (t == 1 ? qmask : kmask), bOb, Lk[t]);
        gemm(bOb, ow + t*WSTEP, WSTEP, ob + t*1024, bM, nullptr, NX, 1024, 1024, 0);
        const float* resid = (t == 0) ? img : bX;
        ln_res<1><<<NX, blk, 0, stream>>>(resid, bM, lng + t*1024, lnb + t*1024, bX, xb);
    }

    // FFN
    gemm(xb, w1, (size_t)FFD * HIDN, b1, nullptr, hb, NX, FFD,  1024, 1);
    gemm(hb, w2, (size_t)FFD * HIDN, b2, bM, nullptr,  NX, 1024, FFD,  0);
    ln_res<0><<<NX, blk, 0, stream>>>(bX, bM, lng + 3*1024, lnb + 3*1024, out, nullptr);
}

// Round 4
// 779.683 us; speedup vs baseline: 5.3444x; 1.3254x over previous
//
#include <hip/hip_runtime.h>
#include <math.h>

#define HIDN 1024
#define NHEADS 16
#define DHEAD 64
#define FFD 4096
#define LN_EPS 1e-6f
#define NEGV -1e9f

typedef __bf16 bf16_t;
typedef __bf16 bf16x8 __attribute__((ext_vector_type(8)));
typedef float f32x4 __attribute__((ext_vector_type(4)));
typedef unsigned short ushort8 __attribute__((ext_vector_type(8)));
typedef unsigned short ushort4v __attribute__((ext_vector_type(4)));

__device__ __forceinline__ unsigned short f2bf(float f) {
    unsigned u = __float_as_uint(f);
    return (unsigned short)((u + 0x7FFFu + ((u >> 16) & 1u)) >> 16);
}
__device__ __forceinline__ float bf2f(unsigned short u) {
    return __uint_as_float((unsigned)u << 16);
}
__device__ __forceinline__ void gld16(const void* g, void* l) {
    __builtin_amdgcn_global_load_lds(
        (const __attribute__((address_space(1))) void*)g,
        (__attribute__((address_space(3))) void*)l, 16, 0, 0);
}

// ---------------------------------------------------------------------------
// bf16 MFMA GEMM: C[M,N] = A[M,K] * W[N,K]^T + bias[N].  (unchanged r3)
// ---------------------------------------------------------------------------
template<int OUT_BF16, int RELU>
__global__ __launch_bounds__(256)
void gemm_mfma(const bf16_t* __restrict__ A, const bf16_t* __restrict__ W,
               const float* __restrict__ bias, float* __restrict__ Cf,
               unsigned short* __restrict__ Cb, int M, int N, int K)
{
    __shared__ __align__(16) bf16_t As[128 * 64];
    __shared__ __align__(16) bf16_t Bs[128 * 64];

    const int tid  = threadIdx.x;
    const int wid  = tid >> 6;
    const int lane = tid & 63;
    const int m0 = blockIdx.x * 128;
    const int n0 = blockIdx.y * 128;
    const int wm = (wid & 1) * 64;
    const int wn = (wid >> 1) * 64;

    const int sr = (wid << 3) + (lane >> 3);
    const int sk = (lane & 7) * 8;
    const bf16_t* pa = A + (size_t)(m0 + sr) * K + sk;
    const bf16_t* pb = W + (size_t)(n0 + sr) * K + sk;
    bf16_t* lA = &As[(wid << 3) * 64];
    bf16_t* lB = &Bs[(wid << 3) * 64];

    const int lr = lane & 15;
    const int lk = (lane >> 4) * 8;
    const bf16_t* fa = &As[(wm + lr) * 64 + lk];
    const bf16_t* fb = &Bs[(wn + lr) * 64 + lk];

    f32x4 acc[4][4];
    #pragma unroll
    for (int i = 0; i < 4; ++i)
        #pragma unroll
        for (int j = 0; j < 4; ++j) acc[i][j] = (f32x4){0.f, 0.f, 0.f, 0.f};

    for (int k0 = 0; k0 < K; k0 += 64) {
        __syncthreads();
        #pragma unroll
        for (int c = 0; c < 4; ++c) {
            gld16(pa + (size_t)c * 32 * K + k0, lA + c * 32 * 64);
            gld16(pb + (size_t)c * 32 * K + k0, lB + c * 32 * 64);
        }
        asm volatile("s_waitcnt vmcnt(0)" ::: "memory");
        __syncthreads();
        #pragma unroll
        for (int kk = 0; kk < 64; kk += 32) {
            bf16x8 a[4], b[4];
            #pragma unroll
            for (int i = 0; i < 4; ++i) {
                a[i] = *(const bf16x8*)(fa + i * 16 * 64 + kk);
                b[i] = *(const bf16x8*)(fb + i * 16 * 64 + kk);
            }
            #pragma unroll
            for (int i = 0; i < 4; ++i)
                #pragma unroll
                for (int j = 0; j < 4; ++j)
                    acc[i][j] = __builtin_amdgcn_mfma_f32_16x16x32_bf16(
                        a[i], b[j], acc[i][j], 0, 0, 0);
        }
    }

    const int er = wm + (lane >> 4) * 4;
    const int ec = wn + (lane & 15);
    float bv[4];
    #pragma unroll
    for (int j = 0; j < 4; ++j) bv[j] = bias[n0 + ec + j * 16];
    #pragma unroll
    for (int i = 0; i < 4; ++i)
        #pragma unroll
        for (int j = 0; j < 4; ++j)
            #pragma unroll
            for (int r = 0; r < 4; ++r) {
                float v = acc[i][j][r] + bv[j];
                if (RELU) v = fmaxf(v, 0.f);
                size_t idx = (size_t)(m0 + er + i * 16 + r) * N + (n0 + ec + j * 16);
                if (OUT_BF16) Cb[idx] = f2bf(v);
                else          Cf[idx] = v;
            }
}

// ---------------------------------------------------------------------------
// MFMA attention. Block = (64 q-rows, head, batch); 4 waves, each wave owns a
// 16-row q strip. Per 64-wide K/V tile:
//   S strip[16q,64k]: 8 mfma (A = Q frag in regs, B = K rows from LDS)
//   wave-parallel online softmax in accumulator layout (k = lane&15 group)
//   P -> bf16 -> per-wave LDS strip; O strip[16q,64d] += P * V^T (8 mfma)
// K staged [64k][72], V staged transposed [64d][72], P [64q][72].
// ---------------------------------------------------------------------------
template<int HAS_MASK>
__global__ __launch_bounds__(256)
void attn_mfma(const bf16_t* __restrict__ Q, const bf16_t* __restrict__ K,
               const bf16_t* __restrict__ V, const int* __restrict__ mask,
               unsigned short* __restrict__ O, int Lk)
{
    __shared__ __align__(16) unsigned short Ks[64][72];   // [k][d]
    __shared__ __align__(16) unsigned short Vt[64][72];   // [d][k]
    __shared__ __align__(16) unsigned short Ps[64][72];   // [q][k]
    __shared__ int smask[64];

    const int tid  = threadIdx.x;
    const int wid  = tid >> 6;
    const int lane = tid & 63;
    const int lo   = lane & 15;
    const int hi   = lane >> 4;
    const int q0   = blockIdx.x * 64;
    const int h    = blockIdx.y;
    const int b    = blockIdx.z;
    const int Lq   = 512;

    // persistent Q fragments: row q0+wid*16+lo, d = kk*32 + hi*8
    bf16x8 qf[2];
    {
        const bf16_t* qp = Q + (size_t)(b*Lq + q0 + wid*16 + lo) * HIDN + h*DHEAD + hi*8;
        qf[0] = *(const bf16x8*)qp;
        qf[1] = *(const bf16x8*)(qp + 32);
    }

    float mrun[4], lrun[4];
    f32x4 Oc[4];
    #pragma unroll
    for (int r = 0; r < 4; ++r) { mrun[r] = -INFINITY; lrun[r] = 0.f; }
    #pragma unroll
    for (int n = 0; n < 4; ++n) Oc[n] = (f32x4){0.f, 0.f, 0.f, 0.f};

    const int sr = tid >> 2;          // 0..63 tile row
    const int sc = (tid & 3) * 16;    // 16 elems per thread

    for (int k0 = 0; k0 < Lk; k0 += 64) {
        // ---- stage K rows, V transposed, mask ----
        {
            const bf16_t* kp = K + (size_t)(b*Lk + k0 + sr) * HIDN + h*DHEAD + sc;
            *(bf16x8*)&Ks[sr][sc]     = *(const bf16x8*)kp;
            *(bf16x8*)&Ks[sr][sc + 8] = *(const bf16x8*)(kp + 8);
            const unsigned short* vp = (const unsigned short*)
                (V + (size_t)(b*Lk + k0 + sr) * HIDN + h*DHEAD + sc);
            ushort8 v0 = *(const ushort8*)vp;
            ushort8 v1 = *(const ushort8*)(vp + 8);
            #pragma unroll
            for (int t = 0; t < 8; ++t) {
                Vt[sc + t][sr]     = v0[t];
                Vt[sc + 8 + t][sr] = v1[t];
            }
            if (HAS_MASK && tid < 64) smask[tid] = mask[b*Lk + k0 + tid];
        }
        __syncthreads();

        // ---- S = (Q K^T) / 8 ----
        f32x4 s[4];
        #pragma unroll
        for (int j = 0; j < 4; ++j) s[j] = (f32x4){0.f, 0.f, 0.f, 0.f};
        #pragma unroll
        for (int kk = 0; kk < 2; ++kk) {
            #pragma unroll
            for (int j = 0; j < 4; ++j) {
                bf16x8 bfrag = *(const bf16x8*)&Ks[j*16 + lo][kk*32 + hi*8];
                s[j] = __builtin_amdgcn_mfma_f32_16x16x32_bf16(qf[kk], bfrag, s[j], 0, 0, 0);
            }
        }
        #pragma unroll
        for (int j = 0; j < 4; ++j) {
            bool msk = HAS_MASK ? (smask[j*16 + lo] != 0) : false;
            #pragma unroll
            for (int r = 0; r < 4; ++r) {
                float sv = s[j][r] * 0.125f;
                s[j][r] = msk ? NEGV : sv;
            }
        }

        // ---- online softmax per q-row (row = hi*4+r; k across lo & j) ----
        #pragma unroll
        for (int r = 0; r < 4; ++r) {
            float tm = fmaxf(fmaxf(s[0][r], s[1][r]), fmaxf(s[2][r], s[3][r]));
            #pragma unroll
            for (int m = 1; m < 16; m <<= 1) tm = fmaxf(tm, __shfl_xor(tm, m));
            float mnew = fmaxf(mrun[r], tm);
            float f = __expf(mrun[r] - mnew);
            float ps = 0.f;
            #pragma unroll
            for (int j = 0; j < 4; ++j) {
                float p = __expf(s[j][r] - mnew);
                s[j][r] = p;
                ps += p;
            }
            #pragma unroll
            for (int m = 1; m < 16; m <<= 1) ps += __shfl_xor(ps, m);
            lrun[r] = lrun[r] * f + ps;
            mrun[r] = mnew;
            #pragma unroll
            for (int n = 0; n < 4; ++n) Oc[n][r] *= f;
            // P -> bf16 LDS (q row = wid*16 + hi*4 + r, k = j*16 + lo)
            #pragma unroll
            for (int j = 0; j < 4; ++j)
                Ps[wid*16 + hi*4 + r][j*16 + lo] = f2bf(s[j][r]);
        }

        // ---- O += P V  (A = P strip, B = Vt rows) ----
        #pragma unroll
        for (int kk = 0; kk < 2; ++kk) {
            bf16x8 pa = *(const bf16x8*)&Ps[wid*16 + lo][kk*32 + hi*8];
            #pragma unroll
            for (int n = 0; n < 4; ++n) {
                bf16x8 vf = *(const bf16x8*)&Vt[n*16 + lo][kk*32 + hi*8];
                Oc[n] = __builtin_amdgcn_mfma_f32_16x16x32_bf16(pa, vf, Oc[n], 0, 0, 0);
            }
        }
        __syncthreads();
    }

    // ---- epilogue: O /= l ----
    #pragma unroll
    for (int r = 0; r < 4; ++r) {
        float inv = 1.f / lrun[r];
        const size_t row = (size_t)(b*Lq + q0 + wid*16 + hi*4 + r) * HIDN + h*DHEAD;
        #pragma unroll
        for (int n = 0; n < 4; ++n)
            O[row + n*16 + lo] = f2bf(Oc[n][r] * inv);
    }
}

// ---------------------------------------------------------------------------
// LayerNorm(X + R) * g + b; fp32 out, optional bf16 twin.  (unchanged r3)
// ---------------------------------------------------------------------------
template<int DUAL>
__global__ __launch_bounds__(256)
void ln_res(const float* __restrict__ X, const float* __restrict__ R,
            const float* __restrict__ G, const float* __restrict__ Bv,
            float* __restrict__ Out, unsigned short* __restrict__ OutB)
{
    const int row = blockIdx.x;
    const int tid = threadIdx.x;
    const size_t base = (size_t)row * HIDN + tid * 4;
    float4 xv = *(const float4*)(X + base);
    float4 rv = *(const float4*)(R + base);
    float y[4] = {xv.x+rv.x, xv.y+rv.y, xv.z+rv.z, xv.w+rv.w};
    float s1 = y[0] + y[1] + y[2] + y[3];
    float s2 = y[0]*y[0] + y[1]*y[1] + y[2]*y[2] + y[3]*y[3];
    #pragma unroll
    for (int m = 1; m < 64; m <<= 1) {
        s1 += __shfl_xor(s1, m);
        s2 += __shfl_xor(s2, m);
    }
    __shared__ float red1[4], red2[4];
    const int wave = tid >> 6, lane = tid & 63;
    if (lane == 0) { red1[wave] = s1; red2[wave] = s2; }
    __syncthreads();
    s1 = red1[0] + red1[1] + red1[2] + red1[3];
    s2 = red2[0] + red2[1] + red2[2] + red2[3];
    const float mean = s1 * (1.f / HIDN);
    const float var  = s2 * (1.f / HIDN) - mean * mean;
    const float inv  = rsqrtf(var + LN_EPS);
    float4 gv = *(const float4*)(G + tid*4);
    float4 bv = *(const float4*)(Bv + tid*4);
    float4 o;
    o.x = gv.x * (y[0]-mean) * inv + bv.x;
    o.y = gv.y * (y[1]-mean) * inv + bv.y;
    o.z = gv.z * (y[2]-mean) * inv + bv.z;
    o.w = gv.w * (y[3]-mean) * inv + bv.w;
    *(float4*)(Out + base) = o;
    if (DUAL) {
        ushort4v ob;
        ob[0] = f2bf(o.x); ob[1] = f2bf(o.y); ob[2] = f2bf(o.z); ob[3] = f2bf(o.w);
        *(ushort4v*)(OutB + base) = ob;
    }
}

// ---------------------------------------------------------------------------
__global__ __launch_bounds__(256)
void cvt_bf16(const float* __restrict__ in, unsigned short* __restrict__ out, int n8)
{
    int i = blockIdx.x * blockDim.x + threadIdx.x;
    const int stride = gridDim.x * blockDim.x;
    for (; i < n8; i += stride) {
        const float4* p = (const float4*)in + (size_t)i * 2;
        float4 a = p[0], b = p[1];
        ushort8 o;
        o[0] = f2bf(a.x); o[1] = f2bf(a.y); o[2] = f2bf(a.z); o[3] = f2bf(a.w);
        o[4] = f2bf(b.x); o[5] = f2bf(b.y); o[6] = f2bf(b.z); o[7] = f2bf(b.w);
        ((ushort8*)out)[i] = o;
    }
}

// ---------------------------------------------------------------------------
extern "C" void kernel_launch(void* const* d_in, const int* in_sizes, int n_in,
                              void* d_out, int out_size, void* d_ws, size_t ws_size,
                              hipStream_t stream)
{
    const float* img   = (const float*)d_in[0];
    const float* ques  = (const float*)d_in[1];
    const float* kg    = (const float*)d_in[2];
    const int*   qmask = (const int*)d_in[3];
    const int*   kmask = (const int*)d_in[4];
    const float* qw = (const float*)d_in[5];
    const float* qb = (const float*)d_in[6];
    const float* kw = (const float*)d_in[7];
    const float* kb = (const float*)d_in[8];
    const float* vw = (const float*)d_in[9];
    const float* vb = (const float*)d_in[10];
    const float* ow = (const float*)d_in[11];
    const float* ob = (const float*)d_in[12];
    const float* w1 = (const float*)d_in[13];
    const float* b1 = (const float*)d_in[14];
    const float* w2 = (const float*)d_in[15];
    const float* b2 = (const float*)d_in[16];
    const float* lng = (const float*)d_in[17];
    const float* lnb = (const float*)d_in[18];
    float* out = (float*)d_out;

    const int B = 16;
    const int NX = B * 512;
    const size_t WSTEP = (size_t)1024 * 1024;
    const size_t MB = (size_t)1 << 20;

    char* wsb = (char*)d_ws;
    float*          bX    = (float*)(wsb);
    float*          bM    = (float*)(wsb + 32*MB);
    unsigned short* bQ    = (unsigned short*)(wsb + 64*MB);
    unsigned short* bK    = (unsigned short*)(wsb + 80*MB);
    unsigned short* bV    = (unsigned short*)(wsb + 96*MB);
    unsigned short* bOb   = (unsigned short*)(wsb + 112*MB);
    unsigned short* xb    = (unsigned short*)(wsb + 128*MB);
    unsigned short* quesb = (unsigned short*)(wsb + 144*MB);
    unsigned short* kgb   = (unsigned short*)(wsb + 146*MB);
    unsigned short* wb    = (unsigned short*)(wsb + 152*MB);
    unsigned short* hb    = (unsigned short*)(wsb + 64*MB);   // overlays bQ..bOb

    dim3 blk(256);
    auto cvt = [&](const float* src, unsigned short* dst, size_t n) {
        int n8 = (int)(n / 8);
        int grid = (n8 + 255) / 256; if (grid > 2048) grid = 2048;
        cvt_bf16<<<grid, blk, 0, stream>>>(src, dst, n8);
    };
    auto gemm = [&](const unsigned short* A, const float* Wsrc, size_t welems,
                    const float* bias, float* Cf, unsigned short* Cb,
                    int M, int N, int K, int relu) {
        cvt(Wsrc, wb, welems);
        dim3 grid(M / 128, N / 128);
        const bf16_t* Ab = (const bf16_t*)A;
        const bf16_t* Wb = (const bf16_t*)wb;
        if (Cb) {
            if (relu) gemm_mfma<1,1><<<grid, blk, 0, stream>>>(Ab, Wb, bias, nullptr, Cb, M, N, K);
            else      gemm_mfma<1,0><<<grid, blk, 0, stream>>>(Ab, Wb, bias, nullptr, Cb, M, N, K);
        } else {
            gemm_mfma<0,0><<<grid, blk, 0, stream>>>(Ab, Wb, bias, Cf, nullptr, M, N, K);
        }
    };

    cvt(img,  xb,    (size_t)NX * HIDN);
    cvt(ques, quesb, (size_t)B * 64 * HIDN);
    cvt(kg,   kgb,   (size_t)B * 128 * HIDN);

    const unsigned short* Akv[3] = {xb, quesb, kgb};
    const int Mkv[3] = {NX, B * 64, B * 128};
    const int Lk[3]  = {512, 64, 128};

    for (int t = 0; t < 3; ++t) {
        gemm(xb,      qw + t*WSTEP, WSTEP, qb + t*1024, nullptr, bQ, NX,     1024, 1024, 0);
        gemm(Akv[t],  kw + t*WSTEP, WSTEP, kb + t*1024, nullptr, bK, Mkv[t], 1024, 1024, 0);
        gemm(Akv[t],  vw + t*WSTEP, WSTEP, vb + t*1024, nullptr, bV, Mkv[t], 1024, 1024, 0);
        if (t == 0)
            attn_mfma<0><<<dim3(8, NHEADS, B), blk, 0, stream>>>(
                (const bf16_t*)bQ, (const bf16_t*)bK, (const bf16_t*)bV, nullptr, bOb, Lk[t]);
        else
            attn_mfma<1><<<dim3(8, NHEADS, B), blk, 0, stream>>>(
                (const bf16_t*)bQ, (const bf16_t*)bK, (const bf16_t*)bV,
                (t == 1 ? qmask : kmask), bOb, Lk[t]);
        gemm(bOb, ow + t*WSTEP, WSTEP, ob + t*1024, bM, nullptr, NX, 1024, 1024, 0);
        const float* resid = (t == 0) ? img : bX;
        ln_res<1><<<NX, blk, 0, stream>>>(resid, bM, lng + t*1024, lnb + t*1024, bX, xb);
    }

    gemm(xb, w1, (size_t)FFD * HIDN, b1, nullptr, hb, NX, FFD,  1024, 1);
    gemm(hb, w2, (size_t)FFD * HIDN, b2, bM, nullptr,  NX, 1024, FFD,  0);
    ln_res<0><<<NX, blk, 0, stream>>>(bX, bM, lng + 3*1024, lnb + 3*1024, out, nullptr);
}

// Round 5
// 694.462 us; speedup vs baseline: 6.0003x; 1.1227x over previous
//
#include <hip/hip_runtime.h>
#include <math.h>

#define HIDN 1024
#define NHEADS 16
#define DHEAD 64
#define FFD 4096
#define LN_EPS 1e-6f
#define NEGV -1e9f

typedef __bf16 bf16_t;
typedef __bf16 bf16x8 __attribute__((ext_vector_type(8)));
typedef float f32x4 __attribute__((ext_vector_type(4)));
typedef unsigned short ushort8 __attribute__((ext_vector_type(8)));
typedef unsigned short ushort4v __attribute__((ext_vector_type(4)));

__device__ __forceinline__ unsigned short f2bf(float f) {
    unsigned u = __float_as_uint(f);
    return (unsigned short)((u + 0x7FFFu + ((u >> 16) & 1u)) >> 16);
}
__device__ __forceinline__ float bf2f(unsigned short u) {
    return __uint_as_float((unsigned)u << 16);
}
__device__ __forceinline__ void gld16(const void* g, void* l) {
    __builtin_amdgcn_global_load_lds(
        (const __attribute__((address_space(1))) void*)g,
        (__attribute__((address_space(3))) void*)l, 16, 0, 0);
}

// ---------------------------------------------------------------------------
// bf16 MFMA GEMM: C[M,N] = A[M,K] * W[N,K]^T + bias, bf16 out, opt ReLU.
// BM=BN=128, BK=64, 4 waves 2x2, m97 staging structure. Bias given as 4
// per-1024-column-segment pointers (a 128-tile never straddles a segment).
// ---------------------------------------------------------------------------
template<int RELU>
__global__ __launch_bounds__(256)
void gemm_mfma(const bf16_t* __restrict__ A, const bf16_t* __restrict__ W,
               const float* __restrict__ ba, const float* __restrict__ bb,
               const float* __restrict__ bc, const float* __restrict__ bd,
               unsigned short* __restrict__ Cb, int M, int N, int K)
{
    __shared__ __align__(16) bf16_t As[128 * 64];
    __shared__ __align__(16) bf16_t Bs[128 * 64];

    const int tid  = threadIdx.x;
    const int wid  = tid >> 6;
    const int lane = tid & 63;
    const int m0 = blockIdx.x * 128;
    const int n0 = blockIdx.y * 128;
    const int wm = (wid & 1) * 64;
    const int wn = (wid >> 1) * 64;

    const int sr = (wid << 3) + (lane >> 3);   // 0..31
    const int sk = (lane & 7) * 8;
    const bf16_t* pa = A + (size_t)(m0 + sr) * K + sk;
    const bf16_t* pb = W + (size_t)(n0 + sr) * K + sk;
    bf16_t* lA = &As[(wid << 3) * 64];
    bf16_t* lB = &Bs[(wid << 3) * 64];

    const int lr = lane & 15;
    const int lk = (lane >> 4) * 8;
    const bf16_t* fa = &As[(wm + lr) * 64 + lk];
    const bf16_t* fb = &Bs[(wn + lr) * 64 + lk];

    f32x4 acc[4][4];
    #pragma unroll
    for (int i = 0; i < 4; ++i)
        #pragma unroll
        for (int j = 0; j < 4; ++j) acc[i][j] = (f32x4){0.f, 0.f, 0.f, 0.f};

    for (int k0 = 0; k0 < K; k0 += 64) {
        __syncthreads();
        #pragma unroll
        for (int c = 0; c < 4; ++c) {
            gld16(pa + (size_t)c * 32 * K + k0, lA + c * 32 * 64);
            gld16(pb + (size_t)c * 32 * K + k0, lB + c * 32 * 64);
        }
        asm volatile("s_waitcnt vmcnt(0)" ::: "memory");
        __syncthreads();
        #pragma unroll
        for (int kk = 0; kk < 64; kk += 32) {
            bf16x8 a[4], b[4];
            #pragma unroll
            for (int i = 0; i < 4; ++i) {
                a[i] = *(const bf16x8*)(fa + i * 16 * 64 + kk);
                b[i] = *(const bf16x8*)(fb + i * 16 * 64 + kk);
            }
            #pragma unroll
            for (int i = 0; i < 4; ++i)
                #pragma unroll
                for (int j = 0; j < 4; ++j)
                    acc[i][j] = __builtin_amdgcn_mfma_f32_16x16x32_bf16(
                        a[i], b[j], acc[i][j], 0, 0, 0);
        }
    }

    const int seg = n0 >> 10;
    const float* bias = (seg == 0) ? ba : (seg == 1) ? bb : (seg == 2) ? bc : bd;
    const int nl = (n0 & 1023);
    const int er = wm + (lane >> 4) * 4;
    const int ec = wn + (lane & 15);
    float bv[4];
    #pragma unroll
    for (int j = 0; j < 4; ++j) bv[j] = bias[nl + ec + j * 16];
    #pragma unroll
    for (int i = 0; i < 4; ++i)
        #pragma unroll
        for (int j = 0; j < 4; ++j)
            #pragma unroll
            for (int r = 0; r < 4; ++r) {
                float v = acc[i][j][r] + bv[j];
                if (RELU) v = fmaxf(v, 0.f);
                Cb[(size_t)(m0 + er + i * 16 + r) * N + (n0 + ec + j * 16)] = f2bf(v);
            }
}

// ---------------------------------------------------------------------------
// MFMA attention, strided Q/K/V (reads fused projection buffers in place).
// Block = (64 q-rows, head, batch); 4 waves; 16x16x32 MFMA; wave-parallel
// online softmax. O written to stride-1024 buffer.
// ---------------------------------------------------------------------------
template<int HAS_MASK>
__global__ __launch_bounds__(256)
void attn_mfma(const bf16_t* __restrict__ Q, const bf16_t* __restrict__ K,
               const bf16_t* __restrict__ V, int qstride, int kvstride,
               const int* __restrict__ mask,
               unsigned short* __restrict__ O, int Lk)
{
    __shared__ __align__(16) unsigned short Ks[64][72];   // [k][d]
    __shared__ __align__(16) unsigned short Vt[64][72];   // [d][k]
    __shared__ __align__(16) unsigned short Ps[64][72];   // [q][k]
    __shared__ int smask[64];

    const int tid  = threadIdx.x;
    const int wid  = tid >> 6;
    const int lane = tid & 63;
    const int lo   = lane & 15;
    const int hi   = lane >> 4;
    const int q0   = blockIdx.x * 64;
    const int h    = blockIdx.y;
    const int b    = blockIdx.z;
    const int Lq   = 512;

    bf16x8 qf[2];
    {
        const bf16_t* qp = Q + (size_t)(b*Lq + q0 + wid*16 + lo) * qstride + h*DHEAD + hi*8;
        qf[0] = *(const bf16x8*)qp;
        qf[1] = *(const bf16x8*)(qp + 32);
    }

    float mrun[4], lrun[4];
    f32x4 Oc[4];
    #pragma unroll
    for (int r = 0; r < 4; ++r) { mrun[r] = -INFINITY; lrun[r] = 0.f; }
    #pragma unroll
    for (int n = 0; n < 4; ++n) Oc[n] = (f32x4){0.f, 0.f, 0.f, 0.f};

    const int sr = tid >> 2;
    const int sc = (tid & 3) * 16;

    for (int k0 = 0; k0 < Lk; k0 += 64) {
        {
            const bf16_t* kp = K + (size_t)(b*Lk + k0 + sr) * kvstride + h*DHEAD + sc;
            *(bf16x8*)&Ks[sr][sc]     = *(const bf16x8*)kp;
            *(bf16x8*)&Ks[sr][sc + 8] = *(const bf16x8*)(kp + 8);
            const unsigned short* vp = (const unsigned short*)
                (V + (size_t)(b*Lk + k0 + sr) * kvstride + h*DHEAD + sc);
            ushort8 v0 = *(const ushort8*)vp;
            ushort8 v1 = *(const ushort8*)(vp + 8);
            #pragma unroll
            for (int t = 0; t < 8; ++t) {
                Vt[sc + t][sr]     = v0[t];
                Vt[sc + 8 + t][sr] = v1[t];
            }
            if (HAS_MASK && tid < 64) smask[tid] = mask[b*Lk + k0 + tid];
        }
        __syncthreads();

        f32x4 s[4];
        #pragma unroll
        for (int j = 0; j < 4; ++j) s[j] = (f32x4){0.f, 0.f, 0.f, 0.f};
        #pragma unroll
        for (int kk = 0; kk < 2; ++kk) {
            #pragma unroll
            for (int j = 0; j < 4; ++j) {
                bf16x8 bfrag = *(const bf16x8*)&Ks[j*16 + lo][kk*32 + hi*8];
                s[j] = __builtin_amdgcn_mfma_f32_16x16x32_bf16(qf[kk], bfrag, s[j], 0, 0, 0);
            }
        }
        #pragma unroll
        for (int j = 0; j < 4; ++j) {
            bool msk = HAS_MASK ? (smask[j*16 + lo] != 0) : false;
            #pragma unroll
            for (int r = 0; r < 4; ++r) {
                float sv = s[j][r] * 0.125f;
                s[j][r] = msk ? NEGV : sv;
            }
        }

        #pragma unroll
        for (int r = 0; r < 4; ++r) {
            float tm = fmaxf(fmaxf(s[0][r], s[1][r]), fmaxf(s[2][r], s[3][r]));
            #pragma unroll
            for (int m = 1; m < 16; m <<= 1) tm = fmaxf(tm, __shfl_xor(tm, m));
            float mnew = fmaxf(mrun[r], tm);
            float f = __expf(mrun[r] - mnew);
            float ps = 0.f;
            #pragma unroll
            for (int j = 0; j < 4; ++j) {
                float p = __expf(s[j][r] - mnew);
                s[j][r] = p;
                ps += p;
            }
            #pragma unroll
            for (int m = 1; m < 16; m <<= 1) ps += __shfl_xor(ps, m);
            lrun[r] = lrun[r] * f + ps;
            mrun[r] = mnew;
            #pragma unroll
            for (int n = 0; n < 4; ++n) Oc[n][r] *= f;
            #pragma unroll
            for (int j = 0; j < 4; ++j)
                Ps[wid*16 + hi*4 + r][j*16 + lo] = f2bf(s[j][r]);
        }

        #pragma unroll
        for (int kk = 0; kk < 2; ++kk) {
            bf16x8 pa = *(const bf16x8*)&Ps[wid*16 + lo][kk*32 + hi*8];
            #pragma unroll
            for (int n = 0; n < 4; ++n) {
                bf16x8 vf = *(const bf16x8*)&Vt[n*16 + lo][kk*32 + hi*8];
                Oc[n] = __builtin_amdgcn_mfma_f32_16x16x32_bf16(pa, vf, Oc[n], 0, 0, 0);
            }
        }
        __syncthreads();
    }

    #pragma unroll
    for (int r = 0; r < 4; ++r) {
        float inv = 1.f / lrun[r];
        const size_t row = (size_t)(b*Lq + q0 + wid*16 + hi*4 + r) * HIDN + h*DHEAD;
        #pragma unroll
        for (int n = 0; n < 4; ++n)
            O[row + n*16 + lo] = f2bf(Oc[n][r] * inv);
    }
}

// ---------------------------------------------------------------------------
// LayerNorm(X + R): X,R bf16; stats fp32; write bf16 (in-place ok) and/or f32.
// ---------------------------------------------------------------------------
template<int WF32, int WBF>
__global__ __launch_bounds__(256)
void ln_res_b(const unsigned short* __restrict__ X, const unsigned short* __restrict__ R,
              const float* __restrict__ G, const float* __restrict__ Bv,
              unsigned short* __restrict__ OutB, float* __restrict__ OutF)
{
    const int row = blockIdx.x;
    const int tid = threadIdx.x;
    const size_t base = (size_t)row * HIDN + tid * 4;
    ushort4v xv = *(const ushort4v*)(X + base);
    ushort4v rv = *(const ushort4v*)(R + base);
    float y[4];
    #pragma unroll
    for (int t = 0; t < 4; ++t) y[t] = bf2f(xv[t]) + bf2f(rv[t]);
    float s1 = y[0] + y[1] + y[2] + y[3];
    float s2 = y[0]*y[0] + y[1]*y[1] + y[2]*y[2] + y[3]*y[3];
    #pragma unroll
    for (int m = 1; m < 64; m <<= 1) {
        s1 += __shfl_xor(s1, m);
        s2 += __shfl_xor(s2, m);
    }
    __shared__ float red1[4], red2[4];
    const int wave = tid >> 6, lane = tid & 63;
    if (lane == 0) { red1[wave] = s1; red2[wave] = s2; }
    __syncthreads();
    s1 = red1[0] + red1[1] + red1[2] + red1[3];
    s2 = red2[0] + red2[1] + red2[2] + red2[3];
    const float mean = s1 * (1.f / HIDN);
    const float var  = s2 * (1.f / HIDN) - mean * mean;
    const float inv  = rsqrtf(var + LN_EPS);
    float4 gv = *(const float4*)(G + tid*4);
    float4 bv = *(const float4*)(Bv + tid*4);
    float o[4];
    o[0] = gv.x * (y[0]-mean) * inv + bv.x;
    o[1] = gv.y * (y[1]-mean) * inv + bv.y;
    o[2] = gv.z * (y[2]-mean) * inv + bv.z;
    o[3] = gv.w * (y[3]-mean) * inv + bv.w;
    if (WBF) {
        ushort4v ob;
        #pragma unroll
        for (int t = 0; t < 4; ++t) ob[t] = f2bf(o[t]);
        *(ushort4v*)(OutB + base) = ob;
    }
    if (WF32) {
        float4 of = {o[0], o[1], o[2], o[3]};
        *(float4*)(OutF + base) = of;
    }
}

// ---------------------------------------------------------------------------
__global__ __launch_bounds__(256)
void cvt_bf16(const float* __restrict__ in, unsigned short* __restrict__ out, int n8)
{
    int i = blockIdx.x * blockDim.x + threadIdx.x;
    const int stride = gridDim.x * blockDim.x;
    for (; i < n8; i += stride) {
        const float4* p = (const float4*)in + (size_t)i * 2;
        float4 a = p[0], b = p[1];
        ushort8 o;
        o[0] = f2bf(a.x); o[1] = f2bf(a.y); o[2] = f2bf(a.z); o[3] = f2bf(a.w);
        o[4] = f2bf(b.x); o[5] = f2bf(b.y); o[6] = f2bf(b.z); o[7] = f2bf(b.w);
        ((ushort8*)out)[i] = o;
    }
}

// ---------------------------------------------------------------------------
extern "C" void kernel_launch(void* const* d_in, const int* in_sizes, int n_in,
                              void* d_out, int out_size, void* d_ws, size_t ws_size,
                              hipStream_t stream)
{
    const float* img   = (const float*)d_in[0];
    const float* ques  = (const float*)d_in[1];
    const float* kg    = (const float*)d_in[2];
    const int*   qmask = (const int*)d_in[3];
    const int*   kmask = (const int*)d_in[4];
    const float* qw = (const float*)d_in[5];
    const float* qb = (const float*)d_in[6];
    const float* kw = (const float*)d_in[7];
    const float* kb = (const float*)d_in[8];
    const float* vw = (const float*)d_in[9];
    const float* vb = (const float*)d_in[10];
    const float* ow = (const float*)d_in[11];
    const float* ob = (const float*)d_in[12];
    const float* w1 = (const float*)d_in[13];
    const float* b1 = (const float*)d_in[14];
    const float* w2 = (const float*)d_in[15];
    const float* b2 = (const float*)d_in[16];
    const float* lng = (const float*)d_in[17];
    const float* lnb = (const float*)d_in[18];
    float* out = (float*)d_out;

    const int B = 16;
    const int NX = B * 512;                    // 8192 rows
    const size_t WSTEP = (size_t)1024 * 1024;
    const size_t MB = (size_t)1 << 20;
    const size_t MELEM = (size_t)1024 * 1024;  // elems per 1024x1024 weight

    char* wsb = (char*)d_ws;
    unsigned short* xb    = (unsigned short*)(wsb);            // 16 MB
    unsigned short* bM    = (unsigned short*)(wsb + 16*MB);    // 16 MB
    unsigned short* bOb   = (unsigned short*)(wsb + 32*MB);    // 16 MB
    unsigned short* quesb = (unsigned short*)(wsb + 48*MB);    //  2 MB
    unsigned short* kgb   = (unsigned short*)(wsb + 50*MB);    //  4 MB
    unsigned short* wcat  = (unsigned short*)(wsb + 56*MB);    // 16 MB staging
    unsigned short* bQKV  = (unsigned short*)(wsb + 72*MB);    // 48 MB (t0 QKV / t1,t2 Q)
    unsigned short* bKV   = (unsigned short*)(wsb + 120*MB);   //  8 MB
    unsigned short* hb    = (unsigned short*)(wsb + 128*MB);   // 64 MB

    dim3 blk(256);
    auto cvt = [&](const float* src, unsigned short* dst, size_t n) {
        int n8 = (int)(n / 8);
        int grid = (n8 + 255) / 256; if (grid > 2048) grid = 2048;
        cvt_bf16<<<grid, blk, 0, stream>>>(src, dst, n8);
    };
    auto gemm = [&](const unsigned short* A, const unsigned short* W,
                    const float* ba, const float* bb_, const float* bc, const float* bd,
                    unsigned short* C, int M, int N, int K, int relu) {
        dim3 grid(M / 128, N / 128);
        if (relu) gemm_mfma<1><<<grid, blk, 0, stream>>>(
            (const bf16_t*)A, (const bf16_t*)W, ba, bb_, bc, bd, C, M, N, K);
        else      gemm_mfma<0><<<grid, blk, 0, stream>>>(
            (const bf16_t*)A, (const bf16_t*)W, ba, bb_, bc, bd, C, M, N, K);
    };

    cvt(img,  xb,    (size_t)NX * HIDN);
    cvt(ques, quesb, (size_t)B * 64 * HIDN);
    cvt(kg,   kgb,   (size_t)B * 128 * HIDN);

    const unsigned short* Akv[3] = {xb, quesb, kgb};
    const int Mkv[3] = {NX, B * 64, B * 128};
    const int Lk[3]  = {512, 64, 128};

    for (int t = 0; t < 3; ++t) {
        if (t == 0) {
            // fused QKV: N = 3072, weight rows [qw; kw; vw]
            cvt(qw + t*WSTEP, wcat,           MELEM);
            cvt(kw + t*WSTEP, wcat + MELEM,   MELEM);
            cvt(vw + t*WSTEP, wcat + 2*MELEM, MELEM);
            gemm(xb, wcat, qb + t*1024, kb + t*1024, vb + t*1024, vb + t*1024,
                 bQKV, NX, 3072, 1024, 0);
            attn_mfma<0><<<dim3(8, NHEADS, B), blk, 0, stream>>>(
                (const bf16_t*)bQKV, (const bf16_t*)bQKV + 1024, (const bf16_t*)bQKV + 2048,
                3072, 3072, nullptr, bOb, Lk[t]);
        } else {
            // Q projection (A = residual stream)
            cvt(qw + t*WSTEP, wcat, MELEM);
            gemm(xb, wcat, qb + t*1024, qb + t*1024, qb + t*1024, qb + t*1024,
                 bQKV, NX, 1024, 1024, 0);
            // fused KV: N = 2048, weight rows [kw; vw]
            cvt(kw + t*WSTEP, wcat,         MELEM);
            cvt(vw + t*WSTEP, wcat + MELEM, MELEM);
            gemm(Akv[t], wcat, kb + t*1024, vb + t*1024, vb + t*1024, vb + t*1024,
                 bKV, Mkv[t], 2048, 1024, 0);
            attn_mfma<1><<<dim3(8, NHEADS, B), blk, 0, stream>>>(
                (const bf16_t*)bQKV, (const bf16_t*)bKV, (const bf16_t*)bKV + 1024,
                1024, 2048, (t == 1 ? qmask : kmask), bOb, Lk[t]);
        }
        // output projection
        cvt(ow + t*WSTEP, wcat, MELEM);
        gemm(bOb, wcat, ob + t*1024, ob + t*1024, ob + t*1024, ob + t*1024,
             bM, NX, 1024, 1024, 0);
        // LayerNorm(residual + proj) -> xb (in place)
        ln_res_b<0,1><<<NX, blk, 0, stream>>>(xb, bM, lng + t*1024, lnb + t*1024, xb, nullptr);
    }

    // FFN
    cvt(w1, wcat, (size_t)FFD * HIDN / 2 * 2);   // 4M elems -> 8 MB bf16
    gemm(xb, wcat, b1, b1 + 1024, b1 + 2048, b1 + 3072, hb, NX, FFD, 1024, 1);
    cvt(w2, wcat, (size_t)HIDN * FFD);           // 4M elems
    gemm(hb, wcat, b2, b2, b2, b2, bM, NX, 1024, 4096, 0);
    ln_res_b<1,0><<<NX, blk, 0, stream>>>(xb, bM, lng + 3*1024, lnb + 3*1024, nullptr, out);
}

// Round 6
// 606.711 us; speedup vs baseline: 6.8681x; 1.1446x over previous
//
#include <hip/hip_runtime.h>
#include <math.h>

#define HIDN 1024
#define NHEADS 16
#define DHEAD 64
#define FFD 4096
#define LN_EPS 1e-6f
#define NEGV -1e9f

typedef __bf16 bf16_t;
typedef __bf16 bf16x8 __attribute__((ext_vector_type(8)));
typedef float f32x4 __attribute__((ext_vector_type(4)));
typedef unsigned short ushort8 __attribute__((ext_vector_type(8)));
typedef unsigned short ushort4v __attribute__((ext_vector_type(4)));

__device__ __forceinline__ unsigned short f2bf(float f) {
    unsigned u = __float_as_uint(f);
    return (unsigned short)((u + 0x7FFFu + ((u >> 16) & 1u)) >> 16);
}
__device__ __forceinline__ float bf2f(unsigned short u) {
    return __uint_as_float((unsigned)u << 16);
}
__device__ __forceinline__ void gld16(const void* g, void* l) {
    __builtin_amdgcn_global_load_lds(
        (const __attribute__((address_space(1))) void*)g,
        (__attribute__((address_space(3))) void*)l, 16, 0, 0);
}

// ---------------------------------------------------------------------------
// bf16 MFMA GEMM: C[M,N] = A[M,K] * W[N,K]^T + bias, bf16 out, opt ReLU.
// BM=BN=128, BK=64, 4 waves 2x2.
// LDS XOR-swizzle (T2): each 64-col row is 8 x 16B chunks; physical chunk p
// of row r holds logical chunk p ^ (r&7). Staging pre-swizzles the GLOBAL
// source (gld_lds dest must stay linear, rule #21); fragment reads XOR the
// chunk index. Kills the 16-way bank conflict of stride-128B ds_read_b128.
// ---------------------------------------------------------------------------
template<int RELU>
__global__ __launch_bounds__(256)
void gemm_mfma(const bf16_t* __restrict__ A, const bf16_t* __restrict__ W,
               const float* __restrict__ ba, const float* __restrict__ bb,
               const float* __restrict__ bc, const float* __restrict__ bd,
               unsigned short* __restrict__ Cb, int M, int N, int K)
{
    __shared__ __align__(16) bf16_t As[128 * 64];
    __shared__ __align__(16) bf16_t Bs[128 * 64];

    const int tid  = threadIdx.x;
    const int wid  = tid >> 6;
    const int lane = tid & 63;
    const int m0 = blockIdx.x * 128;
    const int n0 = blockIdx.y * 128;
    const int wm = (wid & 1) * 64;
    const int wn = (wid >> 1) * 64;

    // staging: row sr (+c*32), logical chunk (lane&7)^(lane>>3) -> physical
    // chunk (lane&7) == linear lane*16B dest. row&7 == lane>>3.
    const int sr = (wid << 3) + (lane >> 3);            // 0..31
    const int sk = (((lane & 7) ^ (lane >> 3)) * 8);    // pre-swizzled source
    const bf16_t* pa = A + (size_t)(m0 + sr) * K + sk;
    const bf16_t* pb = W + (size_t)(n0 + sr) * K + sk;
    bf16_t* lA = &As[(wid << 3) * 64];
    bf16_t* lB = &Bs[(wid << 3) * 64];

    // fragment read: row = wm/wn + lr (+i*16), logical chunk = hi + (kk?4:0),
    // physical chunk = logical ^ (row&7) = logical ^ (lane&7).
    const int lr  = lane & 15;
    const int hi_ = lane >> 4;
    const int ch0 = ((hi_ + 0) ^ (lane & 7)) * 8;   // kk = 0
    const int ch1 = ((hi_ + 4) ^ (lane & 7)) * 8;   // kk = 32
    const bf16_t* fa = &As[(wm + lr) * 64];
    const bf16_t* fb = &Bs[(wn + lr) * 64];

    f32x4 acc[4][4];
    #pragma unroll
    for (int i = 0; i < 4; ++i)
        #pragma unroll
        for (int j = 0; j < 4; ++j) acc[i][j] = (f32x4){0.f, 0.f, 0.f, 0.f};

    for (int k0 = 0; k0 < K; k0 += 64) {
        __syncthreads();
        #pragma unroll
        for (int c = 0; c < 4; ++c) {
            gld16(pa + (size_t)c * 32 * K + k0, lA + c * 32 * 64);
            gld16(pb + (size_t)c * 32 * K + k0, lB + c * 32 * 64);
        }
        asm volatile("s_waitcnt vmcnt(0)" ::: "memory");
        __syncthreads();
        #pragma unroll
        for (int kk = 0; kk < 2; ++kk) {
            const int ch = kk ? ch1 : ch0;
            bf16x8 a[4], b[4];
            #pragma unroll
            for (int i = 0; i < 4; ++i) {
                a[i] = *(const bf16x8*)(fa + i * 16 * 64 + ch);
                b[i] = *(const bf16x8*)(fb + i * 16 * 64 + ch);
            }
            #pragma unroll
            for (int i = 0; i < 4; ++i)
                #pragma unroll
                for (int j = 0; j < 4; ++j)
                    acc[i][j] = __builtin_amdgcn_mfma_f32_16x16x32_bf16(
                        a[i], b[j], acc[i][j], 0, 0, 0);
        }
    }

    const int seg = n0 >> 10;
    const float* bias = (seg == 0) ? ba : (seg == 1) ? bb : (seg == 2) ? bc : bd;
    const int nl = (n0 & 1023);
    const int er = wm + (lane >> 4) * 4;
    const int ec = wn + (lane & 15);
    float bv[4];
    #pragma unroll
    for (int j = 0; j < 4; ++j) bv[j] = bias[nl + ec + j * 16];
    #pragma unroll
    for (int i = 0; i < 4; ++i)
        #pragma unroll
        for (int j = 0; j < 4; ++j)
            #pragma unroll
            for (int r = 0; r < 4; ++r) {
                float v = acc[i][j][r] + bv[j];
                if (RELU) v = fmaxf(v, 0.f);
                Cb[(size_t)(m0 + er + i * 16 + r) * N + (n0 + ec + j * 16)] = f2bf(v);
            }
}

// ---------------------------------------------------------------------------
// MFMA attention, strided Q/K/V (reads fused projection buffers in place).
// ---------------------------------------------------------------------------
template<int HAS_MASK>
__global__ __launch_bounds__(256)
void attn_mfma(const bf16_t* __restrict__ Q, const bf16_t* __restrict__ K,
               const bf16_t* __restrict__ V, int qstride, int kvstride,
               const int* __restrict__ mask,
               unsigned short* __restrict__ O, int Lk)
{
    __shared__ __align__(16) unsigned short Ks[64][72];   // [k][d]
    __shared__ __align__(16) unsigned short Vt[64][72];   // [d][k]
    __shared__ __align__(16) unsigned short Ps[64][72];   // [q][k]
    __shared__ int smask[64];

    const int tid  = threadIdx.x;
    const int wid  = tid >> 6;
    const int lane = tid & 63;
    const int lo   = lane & 15;
    const int hi   = lane >> 4;
    const int q0   = blockIdx.x * 64;
    const int h    = blockIdx.y;
    const int b    = blockIdx.z;
    const int Lq   = 512;

    bf16x8 qf[2];
    {
        const bf16_t* qp = Q + (size_t)(b*Lq + q0 + wid*16 + lo) * qstride + h*DHEAD + hi*8;
        qf[0] = *(const bf16x8*)qp;
        qf[1] = *(const bf16x8*)(qp + 32);
    }

    float mrun[4], lrun[4];
    f32x4 Oc[4];
    #pragma unroll
    for (int r = 0; r < 4; ++r) { mrun[r] = -INFINITY; lrun[r] = 0.f; }
    #pragma unroll
    for (int n = 0; n < 4; ++n) Oc[n] = (f32x4){0.f, 0.f, 0.f, 0.f};

    const int sr = tid >> 2;
    const int sc = (tid & 3) * 16;

    for (int k0 = 0; k0 < Lk; k0 += 64) {
        {
            const bf16_t* kp = K + (size_t)(b*Lk + k0 + sr) * kvstride + h*DHEAD + sc;
            *(bf16x8*)&Ks[sr][sc]     = *(const bf16x8*)kp;
            *(bf16x8*)&Ks[sr][sc + 8] = *(const bf16x8*)(kp + 8);
            const unsigned short* vp = (const unsigned short*)
                (V + (size_t)(b*Lk + k0 + sr) * kvstride + h*DHEAD + sc);
            ushort8 v0 = *(const ushort8*)vp;
            ushort8 v1 = *(const ushort8*)(vp + 8);
            #pragma unroll
            for (int t = 0; t < 8; ++t) {
                Vt[sc + t][sr]     = v0[t];
                Vt[sc + 8 + t][sr] = v1[t];
            }
            if (HAS_MASK && tid < 64) smask[tid] = mask[b*Lk + k0 + tid];
        }
        __syncthreads();

        f32x4 s[4];
        #pragma unroll
        for (int j = 0; j < 4; ++j) s[j] = (f32x4){0.f, 0.f, 0.f, 0.f};
        #pragma unroll
        for (int kk = 0; kk < 2; ++kk) {
            #pragma unroll
            for (int j = 0; j < 4; ++j) {
                bf16x8 bfrag = *(const bf16x8*)&Ks[j*16 + lo][kk*32 + hi*8];
                s[j] = __builtin_amdgcn_mfma_f32_16x16x32_bf16(qf[kk], bfrag, s[j], 0, 0, 0);
            }
        }
        #pragma unroll
        for (int j = 0; j < 4; ++j) {
            bool msk = HAS_MASK ? (smask[j*16 + lo] != 0) : false;
            #pragma unroll
            for (int r = 0; r < 4; ++r) {
                float sv = s[j][r] * 0.125f;
                s[j][r] = msk ? NEGV : sv;
            }
        }

        #pragma unroll
        for (int r = 0; r < 4; ++r) {
            float tm = fmaxf(fmaxf(s[0][r], s[1][r]), fmaxf(s[2][r], s[3][r]));
            #pragma unroll
            for (int m = 1; m < 16; m <<= 1) tm = fmaxf(tm, __shfl_xor(tm, m));
            float mnew = fmaxf(mrun[r], tm);
            float f = __expf(mrun[r] - mnew);
            float ps = 0.f;
            #pragma unroll
            for (int j = 0; j < 4; ++j) {
                float p = __expf(s[j][r] - mnew);
                s[j][r] = p;
                ps += p;
            }
            #pragma unroll
            for (int m = 1; m < 16; m <<= 1) ps += __shfl_xor(ps, m);
            lrun[r] = lrun[r] * f + ps;
            mrun[r] = mnew;
            #pragma unroll
            for (int n = 0; n < 4; ++n) Oc[n][r] *= f;
            #pragma unroll
            for (int j = 0; j < 4; ++j)
                Ps[wid*16 + hi*4 + r][j*16 + lo] = f2bf(s[j][r]);
        }

        #pragma unroll
        for (int kk = 0; kk < 2; ++kk) {
            bf16x8 pa = *(const bf16x8*)&Ps[wid*16 + lo][kk*32 + hi*8];
            #pragma unroll
            for (int n = 0; n < 4; ++n) {
                bf16x8 vf = *(const bf16x8*)&Vt[n*16 + lo][kk*32 + hi*8];
                Oc[n] = __builtin_amdgcn_mfma_f32_16x16x32_bf16(pa, vf, Oc[n], 0, 0, 0);
            }
        }
        __syncthreads();
    }

    #pragma unroll
    for (int r = 0; r < 4; ++r) {
        float inv = 1.f / lrun[r];
        const size_t row = (size_t)(b*Lq + q0 + wid*16 + hi*4 + r) * HIDN + h*DHEAD;
        #pragma unroll
        for (int n = 0; n < 4; ++n)
            O[row + n*16 + lo] = f2bf(Oc[n][r] * inv);
    }
}

// ---------------------------------------------------------------------------
// LayerNorm(X + R): X,R bf16; stats fp32; write bf16 (in-place ok) and/or f32.
// ---------------------------------------------------------------------------
template<int WF32, int WBF>
__global__ __launch_bounds__(256)
void ln_res_b(const unsigned short* __restrict__ X, const unsigned short* __restrict__ R,
              const float* __restrict__ G, const float* __restrict__ Bv,
              unsigned short* __restrict__ OutB, float* __restrict__ OutF)
{
    const int row = blockIdx.x;
    const int tid = threadIdx.x;
    const size_t base = (size_t)row * HIDN + tid * 4;
    ushort4v xv = *(const ushort4v*)(X + base);
    ushort4v rv = *(const ushort4v*)(R + base);
    float y[4];
    #pragma unroll
    for (int t = 0; t < 4; ++t) y[t] = bf2f(xv[t]) + bf2f(rv[t]);
    float s1 = y[0] + y[1] + y[2] + y[3];
    float s2 = y[0]*y[0] + y[1]*y[1] + y[2]*y[2] + y[3]*y[3];
    #pragma unroll
    for (int m = 1; m < 64; m <<= 1) {
        s1 += __shfl_xor(s1, m);
        s2 += __shfl_xor(s2, m);
    }
    __shared__ float red1[4], red2[4];
    const int wave = tid >> 6, lane = tid & 63;
    if (lane == 0) { red1[wave] = s1; red2[wave] = s2; }
    __syncthreads();
    s1 = red1[0] + red1[1] + red1[2] + red1[3];
    s2 = red2[0] + red2[1] + red2[2] + red2[3];
    const float mean = s1 * (1.f / HIDN);
    const float var  = s2 * (1.f / HIDN) - mean * mean;
    const float inv  = rsqrtf(var + LN_EPS);
    float4 gv = *(const float4*)(G + tid*4);
    float4 bv = *(const float4*)(Bv + tid*4);
    float o[4];
    o[0] = gv.x * (y[0]-mean) * inv + bv.x;
    o[1] = gv.y * (y[1]-mean) * inv + bv.y;
    o[2] = gv.z * (y[2]-mean) * inv + bv.z;
    o[3] = gv.w * (y[3]-mean) * inv + bv.w;
    if (WBF) {
        ushort4v ob;
        #pragma unroll
        for (int t = 0; t < 4; ++t) ob[t] = f2bf(o[t]);
        *(ushort4v*)(OutB + base) = ob;
    }
    if (WF32) {
        float4 of = {o[0], o[1], o[2], o[3]};
        *(float4*)(OutF + base) = of;
    }
}

// ---------------------------------------------------------------------------
__global__ __launch_bounds__(256)
void cvt_bf16(const float* __restrict__ in, unsigned short* __restrict__ out, int n8)
{
    int i = blockIdx.x * blockDim.x + threadIdx.x;
    const int stride = gridDim.x * blockDim.x;
    for (; i < n8; i += stride) {
        const float4* p = (const float4*)in + (size_t)i * 2;
        float4 a = p[0], b = p[1];
        ushort8 o;
        o[0] = f2bf(a.x); o[1] = f2bf(a.y); o[2] = f2bf(a.z); o[3] = f2bf(a.w);
        o[4] = f2bf(b.x); o[5] = f2bf(b.y); o[6] = f2bf(b.z); o[7] = f2bf(b.w);
        ((ushort8*)out)[i] = o;
    }
}

// ---------------------------------------------------------------------------
extern "C" void kernel_launch(void* const* d_in, const int* in_sizes, int n_in,
                              void* d_out, int out_size, void* d_ws, size_t ws_size,
                              hipStream_t stream)
{
    const float* img   = (const float*)d_in[0];
    const float* ques  = (const float*)d_in[1];
    const float* kg    = (const float*)d_in[2];
    const int*   qmask = (const int*)d_in[3];
    const int*   kmask = (const int*)d_in[4];
    const float* qw = (const float*)d_in[5];
    const float* qb = (const float*)d_in[6];
    const float* kw = (const float*)d_in[7];
    const float* kb = (const float*)d_in[8];
    const float* vw = (const float*)d_in[9];
    const float* vb = (const float*)d_in[10];
    const float* ow = (const float*)d_in[11];
    const float* ob = (const float*)d_in[12];
    const float* w1 = (const float*)d_in[13];
    const float* b1 = (const float*)d_in[14];
    const float* w2 = (const float*)d_in[15];
    const float* b2 = (const float*)d_in[16];
    const float* lng = (const float*)d_in[17];
    const float* lnb = (const float*)d_in[18];
    float* out = (float*)d_out;

    const int B = 16;
    const int NX = B * 512;                    // 8192 rows
    const size_t WSTEP = (size_t)1024 * 1024;
    const size_t MB = (size_t)1 << 20;
    const size_t MELEM = (size_t)1024 * 1024;  // elems per 1024x1024 weight

    char* wsb = (char*)d_ws;
    unsigned short* xb    = (unsigned short*)(wsb);            // 16 MB
    unsigned short* bM    = (unsigned short*)(wsb + 16*MB);    // 16 MB
    unsigned short* bOb   = (unsigned short*)(wsb + 32*MB);    // 16 MB
    unsigned short* quesb = (unsigned short*)(wsb + 48*MB);    //  2 MB
    unsigned short* kgb   = (unsigned short*)(wsb + 50*MB);    //  4 MB
    unsigned short* wcat  = (unsigned short*)(wsb + 56*MB);    // 16 MB staging
    unsigned short* bQKV  = (unsigned short*)(wsb + 72*MB);    // 48 MB (t0 QKV / t1,t2 Q)
    unsigned short* bKV   = (unsigned short*)(wsb + 120*MB);   //  8 MB
    unsigned short* hb    = (unsigned short*)(wsb + 128*MB);   // 64 MB

    dim3 blk(256);
    auto cvt = [&](const float* src, unsigned short* dst, size_t n) {
        int n8 = (int)(n / 8);
        int grid = (n8 + 255) / 256; if (grid > 2048) grid = 2048;
        cvt_bf16<<<grid, blk, 0, stream>>>(src, dst, n8);
    };
    auto gemm = [&](const unsigned short* A, const unsigned short* W,
                    const float* ba, const float* bb_, const float* bc, const float* bd,
                    unsigned short* C, int M, int N, int K, int relu) {
        dim3 grid(M / 128, N / 128);
        if (relu) gemm_mfma<1><<<grid, blk, 0, stream>>>(
            (const bf16_t*)A, (const bf16_t*)W, ba, bb_, bc, bd, C, M, N, K);
        else      gemm_mfma<0><<<grid, blk, 0, stream>>>(
            (const bf16_t*)A, (const bf16_t*)W, ba, bb_, bc, bd, C, M, N, K);
    };

    cvt(img,  xb,    (size_t)NX * HIDN);
    cvt(ques, quesb, (size_t)B * 64 * HIDN);
    cvt(kg,   kgb,   (size_t)B * 128 * HIDN);

    const unsigned short* Akv[3] = {xb, quesb, kgb};
    const int Mkv[3] = {NX, B * 64, B * 128};
    const int Lk[3]  = {512, 64, 128};

    for (int t = 0; t < 3; ++t) {
        if (t == 0) {
            // fused QKV: N = 3072, weight rows [qw; kw; vw]
            cvt(qw + t*WSTEP, wcat,           MELEM);
            cvt(kw + t*WSTEP, wcat + MELEM,   MELEM);
            cvt(vw + t*WSTEP, wcat + 2*MELEM, MELEM);
            gemm(xb, wcat, qb + t*1024, kb + t*1024, vb + t*1024, vb + t*1024,
                 bQKV, NX, 3072, 1024, 0);
            attn_mfma<0><<<dim3(8, NHEADS, B), blk, 0, stream>>>(
                (const bf16_t*)bQKV, (const bf16_t*)bQKV + 1024, (const bf16_t*)bQKV + 2048,
                3072, 3072, nullptr, bOb, Lk[t]);
        } else {
            // Q projection (A = residual stream)
            cvt(qw + t*WSTEP, wcat, MELEM);
            gemm(xb, wcat, qb + t*1024, qb + t*1024, qb + t*1024, qb + t*1024,
                 bQKV, NX, 1024, 1024, 0);
            // fused KV: N = 2048, weight rows [kw; vw]
            cvt(kw + t*WSTEP, wcat,         MELEM);
            cvt(vw + t*WSTEP, wcat + MELEM, MELEM);
            gemm(Akv[t], wcat, kb + t*1024, vb + t*1024, vb + t*1024, vb + t*1024,
                 bKV, Mkv[t], 2048, 1024, 0);
            attn_mfma<1><<<dim3(8, NHEADS, B), blk, 0, stream>>>(
                (const bf16_t*)bQKV, (const bf16_t*)bKV, (const bf16_t*)bKV + 1024,
                1024, 2048, (t == 1 ? qmask : kmask), bOb, Lk[t]);
        }
        // output projection
        cvt(ow + t*WSTEP, wcat, MELEM);
        gemm(bOb, wcat, ob + t*1024, ob + t*1024, ob + t*1024, ob + t*1024,
             bM, NX, 1024, 1024, 0);
        // LayerNorm(residual + proj) -> xb (in place)
        ln_res_b<0,1><<<NX, blk, 0, stream>>>(xb, bM, lng + t*1024, lnb + t*1024, xb, nullptr);
    }

    // FFN
    cvt(w1, wcat, (size_t)FFD * HIDN);           // 4M elems -> 8 MB bf16
    gemm(xb, wcat, b1, b1 + 1024, b1 + 2048, b1 + 3072, hb, NX, FFD, 1024, 1);
    cvt(w2, wcat, (size_t)HIDN * FFD);           // 4M elems
    gemm(hb, wcat, b2, b2, b2, b2, bM, NX, 1024, 4096, 0);
    ln_res_b<1,0><<<NX, blk, 0, stream>>>(xb, bM, lng + 3*1024, lnb + 3*1024, nullptr, out);
}

// Round 7
// 517.931 us; speedup vs baseline: 8.0454x; 1.1714x over previous
//
#include <hip/hip_runtime.h>
#include <math.h>

#define HIDN 1024
#define NHEADS 16
#define DHEAD 64
#define FFD 4096
#define LN_EPS 1e-6f
#define NEGV -1e9f

typedef __bf16 bf16_t;
typedef __bf16 bf16x8 __attribute__((ext_vector_type(8)));
typedef float f32x4 __attribute__((ext_vector_type(4)));
typedef unsigned short ushort8 __attribute__((ext_vector_type(8)));
typedef unsigned short ushort4v __attribute__((ext_vector_type(4)));

__device__ __forceinline__ unsigned short f2bf(float f) {
    unsigned u = __float_as_uint(f);
    return (unsigned short)((u + 0x7FFFu + ((u >> 16) & 1u)) >> 16);
}
__device__ __forceinline__ float bf2f(unsigned short u) {
    return __uint_as_float((unsigned)u << 16);
}
__device__ __forceinline__ void gld16(const void* g, void* l) {
    __builtin_amdgcn_global_load_lds(
        (const __attribute__((address_space(1))) void*)g,
        (__attribute__((address_space(3))) void*)l, 16, 0, 0);
}

// ---------------------------------------------------------------------------
// bf16 MFMA GEMM: C[M,N] = A[M,K] * W[N,K]^T + bias, bf16 out, opt ReLU.
// BM=BN=128, BK=64, 4 waves 2x2, T2 XOR-swizzled LDS (round 6, conflicts=0).
// Round 7: double-buffered LDS, next-tile global_load_lds issued BEFORE the
// current tile's compute, so HBM latency hides under MFMA (T3 depth-1).
// Buffer reuse safety: a buffer is overwritten only after the barrier that
// follows all (lgkm-complete) reads of it. K must be a multiple of 128.
// ---------------------------------------------------------------------------
template<int RELU>
__global__ __launch_bounds__(256)
void gemm_mfma(const bf16_t* __restrict__ A, const bf16_t* __restrict__ W,
               const float* __restrict__ ba, const float* __restrict__ bb,
               const float* __restrict__ bc, const float* __restrict__ bd,
               unsigned short* __restrict__ Cb, int M, int N, int K)
{
    __shared__ __align__(16) bf16_t As[2][128 * 64];
    __shared__ __align__(16) bf16_t Bs[2][128 * 64];

    const int tid  = threadIdx.x;
    const int wid  = tid >> 6;
    const int lane = tid & 63;
    const int m0 = blockIdx.x * 128;
    const int n0 = blockIdx.y * 128;
    const int wm = (wid & 1) * 64;
    const int wn = (wid >> 1) * 64;

    // staging: physical chunk (lane&7) holds logical chunk (lane&7)^(row&7);
    // row&7 == lane>>3. Source pre-swizzled, LDS dest linear (rule #21).
    const int sr = (wid << 3) + (lane >> 3);            // 0..31
    const int sk = (((lane & 7) ^ (lane >> 3)) * 8);
    const bf16_t* pa = A + (size_t)(m0 + sr) * K + sk;
    const bf16_t* pb = W + (size_t)(n0 + sr) * K + sk;
    const int lofs = (wid << 3) * 64;

    // fragment read: logical chunk = hi + (kk?4:0); physical = logical^(row&7)
    const int lr  = lane & 15;
    const int hi_ = lane >> 4;
    const int ch0 = ((hi_ + 0) ^ (lane & 7)) * 8;   // kk = 0
    const int ch1 = ((hi_ + 4) ^ (lane & 7)) * 8;   // kk = 32

    f32x4 acc[4][4];
    #pragma unroll
    for (int i = 0; i < 4; ++i)
        #pragma unroll
        for (int j = 0; j < 4; ++j) acc[i][j] = (f32x4){0.f, 0.f, 0.f, 0.f};

    auto stage = [&](int buf, int koff) {
        #pragma unroll
        for (int c = 0; c < 4; ++c) {
            gld16(pa + (size_t)c * 32 * K + koff, &As[buf][lofs + c * 32 * 64]);
            gld16(pb + (size_t)c * 32 * K + koff, &Bs[buf][lofs + c * 32 * 64]);
        }
    };
    auto compute = [&](int buf) {
        const bf16_t* fa = &As[buf][(wm + lr) * 64];
        const bf16_t* fb = &Bs[buf][(wn + lr) * 64];
        #pragma unroll
        for (int kk = 0; kk < 2; ++kk) {
            const int ch = kk ? ch1 : ch0;
            bf16x8 a[4], b[4];
            #pragma unroll
            for (int i = 0; i < 4; ++i) {
                a[i] = *(const bf16x8*)(fa + i * 16 * 64 + ch);
                b[i] = *(const bf16x8*)(fb + i * 16 * 64 + ch);
            }
            #pragma unroll
            for (int i = 0; i < 4; ++i)
                #pragma unroll
                for (int j = 0; j < 4; ++j)
                    acc[i][j] = __builtin_amdgcn_mfma_f32_16x16x32_bf16(
                        a[i], b[j], acc[i][j], 0, 0, 0);
        }
    };

    stage(0, 0);
    asm volatile("s_waitcnt vmcnt(0)" ::: "memory");
    __syncthreads();

    for (int k0 = 0; k0 < K; k0 += 128) {
        if (k0 + 64 < K) stage(1, k0 + 64);      // in flight during compute(0)
        compute(0);
        asm volatile("s_waitcnt vmcnt(0)" ::: "memory");
        __syncthreads();
        if (k0 + 128 < K) stage(0, k0 + 128);    // in flight during compute(1)
        compute(1);
        asm volatile("s_waitcnt vmcnt(0)" ::: "memory");
        __syncthreads();
    }

    const int seg = n0 >> 10;
    const float* bias = (seg == 0) ? ba : (seg == 1) ? bb : (seg == 2) ? bc : bd;
    const int nl = (n0 & 1023);
    const int er = wm + (lane >> 4) * 4;
    const int ec = wn + (lane & 15);
    float bv[4];
    #pragma unroll
    for (int j = 0; j < 4; ++j) bv[j] = bias[nl + ec + j * 16];
    #pragma unroll
    for (int i = 0; i < 4; ++i)
        #pragma unroll
        for (int j = 0; j < 4; ++j)
            #pragma unroll
            for (int r = 0; r < 4; ++r) {
                float v = acc[i][j][r] + bv[j];
                if (RELU) v = fmaxf(v, 0.f);
                Cb[(size_t)(m0 + er + i * 16 + r) * N + (n0 + ec + j * 16)] = f2bf(v);
            }
}

// ---------------------------------------------------------------------------
// MFMA attention, strided Q/K/V (reads fused projection buffers in place).
// ---------------------------------------------------------------------------
template<int HAS_MASK>
__global__ __launch_bounds__(256)
void attn_mfma(const bf16_t* __restrict__ Q, const bf16_t* __restrict__ K,
               const bf16_t* __restrict__ V, int qstride, int kvstride,
               const int* __restrict__ mask,
               unsigned short* __restrict__ O, int Lk)
{
    __shared__ __align__(16) unsigned short Ks[64][72];   // [k][d]
    __shared__ __align__(16) unsigned short Vt[64][72];   // [d][k]
    __shared__ __align__(16) unsigned short Ps[64][72];   // [q][k]
    __shared__ int smask[64];

    const int tid  = threadIdx.x;
    const int wid  = tid >> 6;
    const int lane = tid & 63;
    const int lo   = lane & 15;
    const int hi   = lane >> 4;
    const int q0   = blockIdx.x * 64;
    const int h    = blockIdx.y;
    const int b    = blockIdx.z;
    const int Lq   = 512;

    bf16x8 qf[2];
    {
        const bf16_t* qp = Q + (size_t)(b*Lq + q0 + wid*16 + lo) * qstride + h*DHEAD + hi*8;
        qf[0] = *(const bf16x8*)qp;
        qf[1] = *(const bf16x8*)(qp + 32);
    }

    float mrun[4], lrun[4];
    f32x4 Oc[4];
    #pragma unroll
    for (int r = 0; r < 4; ++r) { mrun[r] = -INFINITY; lrun[r] = 0.f; }
    #pragma unroll
    for (int n = 0; n < 4; ++n) Oc[n] = (f32x4){0.f, 0.f, 0.f, 0.f};

    const int sr = tid >> 2;
    const int sc = (tid & 3) * 16;

    for (int k0 = 0; k0 < Lk; k0 += 64) {
        {
            const bf16_t* kp = K + (size_t)(b*Lk + k0 + sr) * kvstride + h*DHEAD + sc;
            *(bf16x8*)&Ks[sr][sc]     = *(const bf16x8*)kp;
            *(bf16x8*)&Ks[sr][sc + 8] = *(const bf16x8*)(kp + 8);
            const unsigned short* vp = (const unsigned short*)
                (V + (size_t)(b*Lk + k0 + sr) * kvstride + h*DHEAD + sc);
            ushort8 v0 = *(const ushort8*)vp;
            ushort8 v1 = *(const ushort8*)(vp + 8);
            #pragma unroll
            for (int t = 0; t < 8; ++t) {
                Vt[sc + t][sr]     = v0[t];
                Vt[sc + 8 + t][sr] = v1[t];
            }
            if (HAS_MASK && tid < 64) smask[tid] = mask[b*Lk + k0 + tid];
        }
        __syncthreads();

        f32x4 s[4];
        #pragma unroll
        for (int j = 0; j < 4; ++j) s[j] = (f32x4){0.f, 0.f, 0.f, 0.f};
        #pragma unroll
        for (int kk = 0; kk < 2; ++kk) {
            #pragma unroll
            for (int j = 0; j < 4; ++j) {
                bf16x8 bfrag = *(const bf16x8*)&Ks[j*16 + lo][kk*32 + hi*8];
                s[j] = __builtin_amdgcn_mfma_f32_16x16x32_bf16(qf[kk], bfrag, s[j], 0, 0, 0);
            }
        }
        #pragma unroll
        for (int j = 0; j < 4; ++j) {
            bool msk = HAS_MASK ? (smask[j*16 + lo] != 0) : false;
            #pragma unroll
            for (int r = 0; r < 4; ++r) {
                float sv = s[j][r] * 0.125f;
                s[j][r] = msk ? NEGV : sv;
            }
        }

        #pragma unroll
        for (int r = 0; r < 4; ++r) {
            float tm = fmaxf(fmaxf(s[0][r], s[1][r]), fmaxf(s[2][r], s[3][r]));
            #pragma unroll
            for (int m = 1; m < 16; m <<= 1) tm = fmaxf(tm, __shfl_xor(tm, m));
            float mnew = fmaxf(mrun[r], tm);
            float f = __expf(mrun[r] - mnew);
            float ps = 0.f;
            #pragma unroll
            for (int j = 0; j < 4; ++j) {
                float p = __expf(s[j][r] - mnew);
                s[j][r] = p;
                ps += p;
            }
            #pragma unroll
            for (int m = 1; m < 16; m <<= 1) ps += __shfl_xor(ps, m);
            lrun[r] = lrun[r] * f + ps;
            mrun[r] = mnew;
            #pragma unroll
            for (int n = 0; n < 4; ++n) Oc[n][r] *= f;
            #pragma unroll
            for (int j = 0; j < 4; ++j)
                Ps[wid*16 + hi*4 + r][j*16 + lo] = f2bf(s[j][r]);
        }

        #pragma unroll
        for (int kk = 0; kk < 2; ++kk) {
            bf16x8 pa = *(const bf16x8*)&Ps[wid*16 + lo][kk*32 + hi*8];
            #pragma unroll
            for (int n = 0; n < 4; ++n) {
                bf16x8 vf = *(const bf16x8*)&Vt[n*16 + lo][kk*32 + hi*8];
                Oc[n] = __builtin_amdgcn_mfma_f32_16x16x32_bf16(pa, vf, Oc[n], 0, 0, 0);
            }
        }
        __syncthreads();
    }

    #pragma unroll
    for (int r = 0; r < 4; ++r) {
        float inv = 1.f / lrun[r];
        const size_t row = (size_t)(b*Lq + q0 + wid*16 + hi*4 + r) * HIDN + h*DHEAD;
        #pragma unroll
        for (int n = 0; n < 4; ++n)
            O[row + n*16 + lo] = f2bf(Oc[n][r] * inv);
    }
}

// ---------------------------------------------------------------------------
// LayerNorm(X + R): X,R bf16; stats fp32; write bf16 (in-place ok) and/or f32.
// ---------------------------------------------------------------------------
template<int WF32, int WBF>
__global__ __launch_bounds__(256)
void ln_res_b(const unsigned short* __restrict__ X, const unsigned short* __restrict__ R,
              const float* __restrict__ G, const float* __restrict__ Bv,
              unsigned short* __restrict__ OutB, float* __restrict__ OutF)
{
    const int row = blockIdx.x;
    const int tid = threadIdx.x;
    const size_t base = (size_t)row * HIDN + tid * 4;
    ushort4v xv = *(const ushort4v*)(X + base);
    ushort4v rv = *(const ushort4v*)(R + base);
    float y[4];
    #pragma unroll
    for (int t = 0; t < 4; ++t) y[t] = bf2f(xv[t]) + bf2f(rv[t]);
    float s1 = y[0] + y[1] + y[2] + y[3];
    float s2 = y[0]*y[0] + y[1]*y[1] + y[2]*y[2] + y[3]*y[3];
    #pragma unroll
    for (int m = 1; m < 64; m <<= 1) {
        s1 += __shfl_xor(s1, m);
        s2 += __shfl_xor(s2, m);
    }
    __shared__ float red1[4], red2[4];
    const int wave = tid >> 6, lane = tid & 63;
    if (lane == 0) { red1[wave] = s1; red2[wave] = s2; }
    __syncthreads();
    s1 = red1[0] + red1[1] + red1[2] + red1[3];
    s2 = red2[0] + red2[1] + red2[2] + red2[3];
    const float mean = s1 * (1.f / HIDN);
    const float var  = s2 * (1.f / HIDN) - mean * mean;
    const float inv  = rsqrtf(var + LN_EPS);
    float4 gv = *(const float4*)(G + tid*4);
    float4 bv = *(const float4*)(Bv + tid*4);
    float o[4];
    o[0] = gv.x * (y[0]-mean) * inv + bv.x;
    o[1] = gv.y * (y[1]-mean) * inv + bv.y;
    o[2] = gv.z * (y[2]-mean) * inv + bv.z;
    o[3] = gv.w * (y[3]-mean) * inv + bv.w;
    if (WBF) {
        ushort4v ob;
        #pragma unroll
        for (int t = 0; t < 4; ++t) ob[t] = f2bf(o[t]);
        *(ushort4v*)(OutB + base) = ob;
    }
    if (WF32) {
        float4 of = {o[0], o[1], o[2], o[3]};
        *(float4*)(OutF + base) = of;
    }
}

// ---------------------------------------------------------------------------
// One-shot fp32 -> bf16 conversion of 31 x 1Mi-element units (weights + acts).
// grid = (512, units); 512 blocks x 256 thr x 8 elems = exactly 1Mi elems.
// ---------------------------------------------------------------------------
struct CvtArgs {
    const float* src[32];
    unsigned short* dst[32];
};

__global__ __launch_bounds__(256)
void cvt_units(CvtArgs args)
{
    const float* s = args.src[blockIdx.y];
    unsigned short* d = args.dst[blockIdx.y];
    const int i = blockIdx.x * 256 + threadIdx.x;   // 0..131071
    const float4* p = (const float4*)s + (size_t)i * 2;
    float4 a = p[0], b = p[1];
    ushort8 o;
    o[0] = f2bf(a.x); o[1] = f2bf(a.y); o[2] = f2bf(a.z); o[3] = f2bf(a.w);
    o[4] = f2bf(b.x); o[5] = f2bf(b.y); o[6] = f2bf(b.z); o[7] = f2bf(b.w);
    ((ushort8*)d)[i] = o;
}

// ---------------------------------------------------------------------------
extern "C" void kernel_launch(void* const* d_in, const int* in_sizes, int n_in,
                              void* d_out, int out_size, void* d_ws, size_t ws_size,
                              hipStream_t stream)
{
    const float* img   = (const float*)d_in[0];
    const float* ques  = (const float*)d_in[1];
    const float* kg    = (const float*)d_in[2];
    const int*   qmask = (const int*)d_in[3];
    const int*   kmask = (const int*)d_in[4];
    const float* qw = (const float*)d_in[5];
    const float* qb = (const float*)d_in[6];
    const float* kw = (const float*)d_in[7];
    const float* kb = (const float*)d_in[8];
    const float* vw = (const float*)d_in[9];
    const float* vb = (const float*)d_in[10];
    const float* ow = (const float*)d_in[11];
    const float* ob = (const float*)d_in[12];
    const float* w1 = (const float*)d_in[13];
    const float* b1 = (const float*)d_in[14];
    const float* w2 = (const float*)d_in[15];
    const float* b2 = (const float*)d_in[16];
    const float* lng = (const float*)d_in[17];
    const float* lnb = (const float*)d_in[18];
    float* out = (float*)d_out;

    const int B = 16;
    const int NX = B * 512;                    // 8192 rows
    const size_t WSTEP = (size_t)1024 * 1024;
    const size_t MB = (size_t)1 << 20;
    const size_t MELEM = (size_t)1024 * 1024;

    char* wsb = (char*)d_ws;
    unsigned short* xb    = (unsigned short*)(wsb);            // 16 MB
    unsigned short* bM    = (unsigned short*)(wsb + 16*MB);    // 16 MB
    unsigned short* bOb   = (unsigned short*)(wsb + 32*MB);    // 16 MB
    unsigned short* quesb = (unsigned short*)(wsb + 48*MB);    //  2 MB
    unsigned short* kgb   = (unsigned short*)(wsb + 50*MB);    //  4 MB
    unsigned short* wa    = (unsigned short*)(wsb + 56*MB);    // 40 MB weight arena
    unsigned short* bQKV  = (unsigned short*)(wsb + 96*MB);    // 48 MB
    unsigned short* bKV   = (unsigned short*)(wsb + 144*MB);   //  8 MB
    unsigned short* hb    = (unsigned short*)(wsb + 96*MB);    // 64 MB, overlays bQKV/bKV (dead in FFN)

    // weight arena unit map (1 Mi elems each):
    //  0-2: qw0,kw0,vw0 (fused QKV)   3: qw1   4-5: kw1,vw1   6: qw2
    //  7-8: kw2,vw2   9-11: ow0,ow1,ow2   12-15: w1   16-19: w2
    CvtArgs ca;
    int u = 0;
    auto addu = [&](const float* src, int melems, unsigned short* dst) {
        for (int i = 0; i < melems; ++i) {
            ca.src[u] = src + (size_t)i * MELEM;
            ca.dst[u] = dst + (size_t)i * MELEM;
            ++u;
        }
    };
    addu(qw + 0*WSTEP, 1, wa + 0*MELEM);
    addu(kw + 0*WSTEP, 1, wa + 1*MELEM);
    addu(vw + 0*WSTEP, 1, wa + 2*MELEM);
    addu(qw + 1*WSTEP, 1, wa + 3*MELEM);
    addu(kw + 1*WSTEP, 1, wa + 4*MELEM);
    addu(vw + 1*WSTEP, 1, wa + 5*MELEM);
    addu(qw + 2*WSTEP, 1, wa + 6*MELEM);
    addu(kw + 2*WSTEP, 1, wa + 7*MELEM);
    addu(vw + 2*WSTEP, 1, wa + 8*MELEM);
    addu(ow + 0*WSTEP, 1, wa + 9*MELEM);
    addu(ow + 1*WSTEP, 1, wa + 10*MELEM);
    addu(ow + 2*WSTEP, 1, wa + 11*MELEM);
    addu(w1, 4, wa + 12*MELEM);
    addu(w2, 4, wa + 16*MELEM);
    addu(img,  8, xb);
    addu(ques, 1, quesb);
    addu(kg,   2, kgb);

    dim3 blk(256);
    cvt_units<<<dim3(512, u), blk, 0, stream>>>(ca);

    auto gemm = [&](const unsigned short* A, const unsigned short* W,
                    const float* ba, const float* bb_, const float* bc, const float* bd,
                    unsigned short* C, int M, int N, int K, int relu) {
        dim3 grid(M / 128, N / 128);
        if (relu) gemm_mfma<1><<<grid, blk, 0, stream>>>(
            (const bf16_t*)A, (const bf16_t*)W, ba, bb_, bc, bd, C, M, N, K);
        else      gemm_mfma<0><<<grid, blk, 0, stream>>>(
            (const bf16_t*)A, (const bf16_t*)W, ba, bb_, bc, bd, C, M, N, K);
    };

    const unsigned short* Akv[3] = {xb, quesb, kgb};
    const int Mkv[3] = {NX, B * 64, B * 128};
    const int Lk[3]  = {512, 64, 128};

    for (int t = 0; t < 3; ++t) {
        if (t == 0) {
            gemm(xb, wa + 0*MELEM, qb + 0, kb + 0, vb + 0, vb + 0,
                 bQKV, NX, 3072, 1024, 0);
            attn_mfma<0><<<dim3(8, NHEADS, B), blk, 0, stream>>>(
                (const bf16_t*)bQKV, (const bf16_t*)bQKV + 1024, (const bf16_t*)bQKV + 2048,
                3072, 3072, nullptr, bOb, Lk[t]);
        } else {
            gemm(xb, wa + (t == 1 ? 3 : 6)*MELEM,
                 qb + t*1024, qb + t*1024, qb + t*1024, qb + t*1024,
                 bQKV, NX, 1024, 1024, 0);
            gemm(Akv[t], wa + (t == 1 ? 4 : 7)*MELEM,
                 kb + t*1024, vb + t*1024, vb + t*1024, vb + t*1024,
                 bKV, Mkv[t], 2048, 1024, 0);
            attn_mfma<1><<<dim3(8, NHEADS, B), blk, 0, stream>>>(
                (const bf16_t*)bQKV, (const bf16_t*)bKV, (const bf16_t*)bKV + 1024,
                1024, 2048, (t == 1 ? qmask : kmask), bOb, Lk[t]);
        }
        gemm(bOb, wa + (9 + t)*MELEM,
             ob + t*1024, ob + t*1024, ob + t*1024, ob + t*1024,
             bM, NX, 1024, 1024, 0);
        ln_res_b<0,1><<<NX, blk, 0, stream>>>(xb, bM, lng + t*1024, lnb + t*1024, xb, nullptr);
    }

    // FFN
    gemm(xb, wa + 12*MELEM, b1, b1 + 1024, b1 + 2048, b1 + 3072, hb, NX, FFD, 1024, 1);
    gemm(hb, wa + 16*MELEM, b2, b2, b2, b2, bM, NX, 1024, 4096, 0);
    ln_res_b<1,0><<<NX, blk, 0, stream>>>(xb, bM, lng + 3*1024, lnb + 3*1024, nullptr, out);
}

// Round 8
// 505.552 us; speedup vs baseline: 8.2424x; 1.0245x over previous
//
#include <hip/hip_runtime.h>
#include <math.h>

#define HIDN 1024
#define NHEADS 16
#define DHEAD 64
#define FFD 4096
#define LN_EPS 1e-6f
#define NEGV -1e9f

typedef __bf16 bf16_t;
typedef __bf16 bf16x8 __attribute__((ext_vector_type(8)));
typedef float f32x4 __attribute__((ext_vector_type(4)));
typedef unsigned short ushort8 __attribute__((ext_vector_type(8)));
typedef unsigned short ushort4v __attribute__((ext_vector_type(4)));

__device__ __forceinline__ unsigned short f2bf(float f) {
    unsigned u = __float_as_uint(f);
    return (unsigned short)((u + 0x7FFFu + ((u >> 16) & 1u)) >> 16);
}
__device__ __forceinline__ float bf2f(unsigned short u) {
    return __uint_as_float((unsigned)u << 16);
}
__device__ __forceinline__ void gld16(const void* g, void* l) {
    __builtin_amdgcn_global_load_lds(
        (const __attribute__((address_space(1))) void*)g,
        (__attribute__((address_space(3))) void*)l, 16, 0, 0);
}

// ---------------------------------------------------------------------------
// bf16 MFMA GEMM (unchanged round 7): BM=BN=128, BK=64, 4 waves, T2 swizzle,
// double-buffered LDS with issue-early staging.
// ---------------------------------------------------------------------------
template<int RELU>
__global__ __launch_bounds__(256)
void gemm_mfma(const bf16_t* __restrict__ A, const bf16_t* __restrict__ W,
               const float* __restrict__ ba, const float* __restrict__ bb,
               const float* __restrict__ bc, const float* __restrict__ bd,
               unsigned short* __restrict__ Cb, int M, int N, int K)
{
    __shared__ __align__(16) bf16_t As[2][128 * 64];
    __shared__ __align__(16) bf16_t Bs[2][128 * 64];

    const int tid  = threadIdx.x;
    const int wid  = tid >> 6;
    const int lane = tid & 63;
    const int m0 = blockIdx.x * 128;
    const int n0 = blockIdx.y * 128;
    const int wm = (wid & 1) * 64;
    const int wn = (wid >> 1) * 64;

    const int sr = (wid << 3) + (lane >> 3);            // 0..31
    const int sk = (((lane & 7) ^ (lane >> 3)) * 8);
    const bf16_t* pa = A + (size_t)(m0 + sr) * K + sk;
    const bf16_t* pb = W + (size_t)(n0 + sr) * K + sk;
    const int lofs = (wid << 3) * 64;

    const int lr  = lane & 15;
    const int hi_ = lane >> 4;
    const int ch0 = ((hi_ + 0) ^ (lane & 7)) * 8;   // kk = 0
    const int ch1 = ((hi_ + 4) ^ (lane & 7)) * 8;   // kk = 32

    f32x4 acc[4][4];
    #pragma unroll
    for (int i = 0; i < 4; ++i)
        #pragma unroll
        for (int j = 0; j < 4; ++j) acc[i][j] = (f32x4){0.f, 0.f, 0.f, 0.f};

    auto stage = [&](int buf, int koff) {
        #pragma unroll
        for (int c = 0; c < 4; ++c) {
            gld16(pa + (size_t)c * 32 * K + koff, &As[buf][lofs + c * 32 * 64]);
            gld16(pb + (size_t)c * 32 * K + koff, &Bs[buf][lofs + c * 32 * 64]);
        }
    };
    auto compute = [&](int buf) {
        const bf16_t* fa = &As[buf][(wm + lr) * 64];
        const bf16_t* fb = &Bs[buf][(wn + lr) * 64];
        #pragma unroll
        for (int kk = 0; kk < 2; ++kk) {
            const int ch = kk ? ch1 : ch0;
            bf16x8 a[4], b[4];
            #pragma unroll
            for (int i = 0; i < 4; ++i) {
                a[i] = *(const bf16x8*)(fa + i * 16 * 64 + ch);
                b[i] = *(const bf16x8*)(fb + i * 16 * 64 + ch);
            }
            #pragma unroll
            for (int i = 0; i < 4; ++i)
                #pragma unroll
                for (int j = 0; j < 4; ++j)
                    acc[i][j] = __builtin_amdgcn_mfma_f32_16x16x32_bf16(
                        a[i], b[j], acc[i][j], 0, 0, 0);
        }
    };

    stage(0, 0);
    asm volatile("s_waitcnt vmcnt(0)" ::: "memory");
    __syncthreads();

    for (int k0 = 0; k0 < K; k0 += 128) {
        if (k0 + 64 < K) stage(1, k0 + 64);
        compute(0);
        asm volatile("s_waitcnt vmcnt(0)" ::: "memory");
        __syncthreads();
        if (k0 + 128 < K) stage(0, k0 + 128);
        compute(1);
        asm volatile("s_waitcnt vmcnt(0)" ::: "memory");
        __syncthreads();
    }

    const int seg = n0 >> 10;
    const float* bias = (seg == 0) ? ba : (seg == 1) ? bb : (seg == 2) ? bc : bd;
    const int nl = (n0 & 1023);
    const int er = wm + (lane >> 4) * 4;
    const int ec = wn + (lane & 15);
    float bv[4];
    #pragma unroll
    for (int j = 0; j < 4; ++j) bv[j] = bias[nl + ec + j * 16];
    #pragma unroll
    for (int i = 0; i < 4; ++i)
        #pragma unroll
        for (int j = 0; j < 4; ++j)
            #pragma unroll
            for (int r = 0; r < 4; ++r) {
                float v = acc[i][j][r] + bv[j];
                if (RELU) v = fmaxf(v, 0.f);
                Cb[(size_t)(m0 + er + i * 16 + r) * N + (n0 + ec + j * 16)] = f2bf(v);
            }
}

// ---------------------------------------------------------------------------
// MFMA attention v2: ONE block per (head, batch) = 256 blocks, 512 threads
// (8 waves), each wave owns 4 strips of 16 q-rows -> all 512 q rows/block.
// K/V head slice is fetched exactly once. Per 64-wide K/V tile:
//   waves 0-3 stage K rows, waves 4-7 stage V transposed (parallel);
//   XOR-swizzled columns (col ^= ((row>>3)&7)<<3) on both store & read;
//   async-STAGE split: next tile's global loads issue before compute (T14).
// Ks[k][d'], Vt[d][k'], Ps[128][72] per-wave rows (no cross-wave deps).
// ---------------------------------------------------------------------------
template<int HAS_MASK>
__global__ __launch_bounds__(512, 2)
void attn_mfma(const bf16_t* __restrict__ Q, const bf16_t* __restrict__ K,
               const bf16_t* __restrict__ V, int qstride, int kvstride,
               const int* __restrict__ mask,
               unsigned short* __restrict__ O, int Lk)
{
    __shared__ __align__(16) unsigned short Ks[64][72];    // [k][d] swz
    __shared__ __align__(16) unsigned short Vt[64][72];    // [d][k] swz
    __shared__ __align__(16) unsigned short Ps[128][72];   // [q][k] linear
    __shared__ int smask[64];

    const int tid  = threadIdx.x;
    const int wid  = tid >> 6;       // 0..7
    const int lane = tid & 63;
    const int lo   = lane & 15;
    const int hi   = lane >> 4;
    const int h    = blockIdx.x;
    const int b    = blockIdx.y;
    const int Lq   = 512;

    // persistent Q fragments: strip s4 covers rows s4*128 + wid*16 + [0,16)
    bf16x8 qf[4][2];
    #pragma unroll
    for (int s4 = 0; s4 < 4; ++s4) {
        const bf16_t* qp = Q + (size_t)(b*Lq + s4*128 + wid*16 + lo) * qstride
                             + h*DHEAD + hi*8;
        qf[s4][0] = *(const bf16x8*)qp;
        qf[s4][1] = *(const bf16x8*)(qp + 32);
    }

    float mrun[4][4], lrun[4][4];
    f32x4 Oc[4][4];
    #pragma unroll
    for (int s4 = 0; s4 < 4; ++s4)
        #pragma unroll
        for (int r = 0; r < 4; ++r) {
            mrun[s4][r] = -INFINITY; lrun[s4][r] = 0.f;
            Oc[s4][r] = (f32x4){0.f, 0.f, 0.f, 0.f};
        }

    // staging regs (async split: load early, store after barrier)
    ushort8 r0, r1;
    int mreg = 0;

    auto load_tile = [&](int k0) {
        if (tid < 256) {                      // waves 0-3: K rows
            const int sr = tid >> 2, sc = (tid & 3) * 16;
            const unsigned short* kp = (const unsigned short*)
                (K + (size_t)(b*Lk + k0 + sr) * kvstride + h*DHEAD + sc);
            r0 = *(const ushort8*)kp;
            r1 = *(const ushort8*)(kp + 8);
        } else {                              // waves 4-7: V rows
            const int t2 = tid - 256, sr = t2 >> 2, sc = (t2 & 3) * 16;
            const unsigned short* vp = (const unsigned short*)
                (V + (size_t)(b*Lk + k0 + sr) * kvstride + h*DHEAD + sc);
            r0 = *(const ushort8*)vp;
            r1 = *(const ushort8*)(vp + 8);
        }
        if (HAS_MASK && tid < 64) mreg = mask[b*Lk + k0 + tid];
    };
    auto store_tile = [&]() {
        if (tid < 256) {                      // K: row sr, swizzled cols
            const int sr = tid >> 2, sc = (tid & 3) * 16;
            const int x = ((sr >> 3) & 7) << 3;
            *(ushort8*)&Ks[sr][sc ^ x]       = r0;
            *(ushort8*)&Ks[sr][(sc + 8) ^ x] = r1;
        } else {                              // V: transpose, swizzled cols
            const int t2 = tid - 256, sr = t2 >> 2, sc = (t2 & 3) * 16;
            #pragma unroll
            for (int t = 0; t < 8; ++t) {
                const int d0 = sc + t, d1 = sc + 8 + t;
                Vt[d0][sr ^ (((d0 >> 3) & 7) << 3)] = r0[t];
                Vt[d1][sr ^ (((d1 >> 3) & 7) << 3)] = r1[t];
            }
        }
        if (HAS_MASK && tid < 64) smask[tid] = mreg;
    };

    load_tile(0);
    store_tile();
    __syncthreads();

    int k0 = 0;
    while (true) {
        const bool more = (k0 + 64 < Lk);
        if (more) load_tile(k0 + 64);         // in flight during compute

        #pragma unroll
        for (int s4 = 0; s4 < 4; ++s4) {
            // ---- S = (Q K^T) / 8 ----
            f32x4 sv[4];
            #pragma unroll
            for (int j = 0; j < 4; ++j) sv[j] = (f32x4){0.f, 0.f, 0.f, 0.f};
            #pragma unroll
            for (int kk = 0; kk < 2; ++kk) {
                #pragma unroll
                for (int j = 0; j < 4; ++j) {
                    const int krow = j*16 + lo;
                    const int kcol = (kk*32 + hi*8) ^ (((krow >> 3) & 7) << 3);
                    bf16x8 bfrag = *(const bf16x8*)&Ks[krow][kcol];
                    sv[j] = __builtin_amdgcn_mfma_f32_16x16x32_bf16(
                        qf[s4][kk], bfrag, sv[j], 0, 0, 0);
                }
            }
            #pragma unroll
            for (int j = 0; j < 4; ++j) {
                bool msk = HAS_MASK ? (smask[j*16 + lo] != 0) : false;
                #pragma unroll
                for (int r = 0; r < 4; ++r) {
                    float x = sv[j][r] * 0.125f;
                    sv[j][r] = msk ? NEGV : x;
                }
            }
            // ---- online softmax (q row = hi*4 + r; k over j,lo) ----
            #pragma unroll
            for (int r = 0; r < 4; ++r) {
                float tm = fmaxf(fmaxf(sv[0][r], sv[1][r]), fmaxf(sv[2][r], sv[3][r]));
                #pragma unroll
                for (int m = 1; m < 16; m <<= 1) tm = fmaxf(tm, __shfl_xor(tm, m));
                float mnew = fmaxf(mrun[s4][r], tm);
                float f = __expf(mrun[s4][r] - mnew);
                float ps = 0.f;
                #pragma unroll
                for (int j = 0; j < 4; ++j) {
                    float p = __expf(sv[j][r] - mnew);
                    sv[j][r] = p;
                    ps += p;
                }
                #pragma unroll
                for (int m = 1; m < 16; m <<= 1) ps += __shfl_xor(ps, m);
                lrun[s4][r] = lrun[s4][r] * f + ps;
                mrun[s4][r] = mnew;
                #pragma unroll
                for (int n = 0; n < 4; ++n) Oc[s4][n][r] *= f;
                #pragma unroll
                for (int j = 0; j < 4; ++j)
                    Ps[wid*16 + hi*4 + r][j*16 + lo] = f2bf(sv[j][r]);
            }
            // ---- O += P V ----
            #pragma unroll
            for (int kk = 0; kk < 2; ++kk) {
                bf16x8 pa = *(const bf16x8*)&Ps[wid*16 + lo][kk*32 + hi*8];
                #pragma unroll
                for (int n = 0; n < 4; ++n) {
                    const int vrow = n*16 + lo;
                    const int vcol = (kk*32 + hi*8) ^ (((vrow >> 3) & 7) << 3);
                    bf16x8 vf = *(const bf16x8*)&Vt[vrow][vcol];
                    Oc[s4][n] = __builtin_amdgcn_mfma_f32_16x16x32_bf16(
                        pa, vf, Oc[s4][n], 0, 0, 0);
                }
            }
        }

        if (!more) break;
        __syncthreads();          // everyone done reading Ks/Vt/smask
        store_tile();             // write prefetched regs
        __syncthreads();          // tile ready
        k0 += 64;
    }

    // ---- epilogue: O /= l ----
    #pragma unroll
    for (int s4 = 0; s4 < 4; ++s4)
        #pragma unroll
        for (int r = 0; r < 4; ++r) {
            float inv = 1.f / lrun[s4][r];
            const size_t row = (size_t)(b*Lq + s4*128 + wid*16 + hi*4 + r) * HIDN
                             + h*DHEAD;
            #pragma unroll
            for (int n = 0; n < 4; ++n)
                O[row + n*16 + lo] = f2bf(Oc[s4][n][r] * inv);
        }
}

// ---------------------------------------------------------------------------
// LayerNorm(X + R): X,R bf16; stats fp32; write bf16 (in-place ok) and/or f32.
// ---------------------------------------------------------------------------
template<int WF32, int WBF>
__global__ __launch_bounds__(256)
void ln_res_b(const unsigned short* __restrict__ X, const unsigned short* __restrict__ R,
              const float* __restrict__ G, const float* __restrict__ Bv,
              unsigned short* __restrict__ OutB, float* __restrict__ OutF)
{
    const int row = blockIdx.x;
    const int tid = threadIdx.x;
    const size_t base = (size_t)row * HIDN + tid * 4;
    ushort4v xv = *(const ushort4v*)(X + base);
    ushort4v rv = *(const ushort4v*)(R + base);
    float y[4];
    #pragma unroll
    for (int t = 0; t < 4; ++t) y[t] = bf2f(xv[t]) + bf2f(rv[t]);
    float s1 = y[0] + y[1] + y[2] + y[3];
    float s2 = y[0]*y[0] + y[1]*y[1] + y[2]*y[2] + y[3]*y[3];
    #pragma unroll
    for (int m = 1; m < 64; m <<= 1) {
        s1 += __shfl_xor(s1, m);
        s2 += __shfl_xor(s2, m);
    }
    __shared__ float red1[4], red2[4];
    const int wave = tid >> 6, lane = tid & 63;
    if (lane == 0) { red1[wave] = s1; red2[wave] = s2; }
    __syncthreads();
    s1 = red1[0] + red1[1] + red1[2] + red1[3];
    s2 = red2[0] + red2[1] + red2[2] + red2[3];
    const float mean = s1 * (1.f / HIDN);
    const float var  = s2 * (1.f / HIDN) - mean * mean;
    const float inv  = rsqrtf(var + LN_EPS);
    float4 gv = *(const float4*)(G + tid*4);
    float4 bv = *(const float4*)(Bv + tid*4);
    float o[4];
    o[0] = gv.x * (y[0]-mean) * inv + bv.x;
    o[1] = gv.y * (y[1]-mean) * inv + bv.y;
    o[2] = gv.z * (y[2]-mean) * inv + bv.z;
    o[3] = gv.w * (y[3]-mean) * inv + bv.w;
    if (WBF) {
        ushort4v ob;
        #pragma unroll
        for (int t = 0; t < 4; ++t) ob[t] = f2bf(o[t]);
        *(ushort4v*)(OutB + base) = ob;
    }
    if (WF32) {
        float4 of = {o[0], o[1], o[2], o[3]};
        *(float4*)(OutF + base) = of;
    }
}

// ---------------------------------------------------------------------------
// One-shot fp32 -> bf16 conversion of 1Mi-element units (weights + acts).
// ---------------------------------------------------------------------------
struct CvtArgs {
    const float* src[32];
    unsigned short* dst[32];
};

__global__ __launch_bounds__(256)
void cvt_units(CvtArgs args)
{
    const float* s = args.src[blockIdx.y];
    unsigned short* d = args.dst[blockIdx.y];
    const int i = blockIdx.x * 256 + threadIdx.x;   // 0..131071
    const float4* p = (const float4*)s + (size_t)i * 2;
    float4 a = p[0], b = p[1];
    ushort8 o;
    o[0] = f2bf(a.x); o[1] = f2bf(a.y); o[2] = f2bf(a.z); o[3] = f2bf(a.w);
    o[4] = f2bf(b.x); o[5] = f2bf(b.y); o[6] = f2bf(b.z); o[7] = f2bf(b.w);
    ((ushort8*)d)[i] = o;
}

// ---------------------------------------------------------------------------
extern "C" void kernel_launch(void* const* d_in, const int* in_sizes, int n_in,
                              void* d_out, int out_size, void* d_ws, size_t ws_size,
                              hipStream_t stream)
{
    const float* img   = (const float*)d_in[0];
    const float* ques  = (const float*)d_in[1];
    const float* kg    = (const float*)d_in[2];
    const int*   qmask = (const int*)d_in[3];
    const int*   kmask = (const int*)d_in[4];
    const float* qw = (const float*)d_in[5];
    const float* qb = (const float*)d_in[6];
    const float* kw = (const float*)d_in[7];
    const float* kb = (const float*)d_in[8];
    const float* vw = (const float*)d_in[9];
    const float* vb = (const float*)d_in[10];
    const float* ow = (const float*)d_in[11];
    const float* ob = (const float*)d_in[12];
    const float* w1 = (const float*)d_in[13];
    const float* b1 = (const float*)d_in[14];
    const float* w2 = (const float*)d_in[15];
    const float* b2 = (const float*)d_in[16];
    const float* lng = (const float*)d_in[17];
    const float* lnb = (const float*)d_in[18];
    float* out = (float*)d_out;

    const int B = 16;
    const int NX = B * 512;                    // 8192 rows
    const size_t WSTEP = (size_t)1024 * 1024;
    const size_t MB = (size_t)1 << 20;
    const size_t MELEM = (size_t)1024 * 1024;

    char* wsb = (char*)d_ws;
    unsigned short* xb    = (unsigned short*)(wsb);            // 16 MB
    unsigned short* bM    = (unsigned short*)(wsb + 16*MB);    // 16 MB
    unsigned short* bOb   = (unsigned short*)(wsb + 32*MB);    // 16 MB
    unsigned short* quesb = (unsigned short*)(wsb + 48*MB);    //  2 MB
    unsigned short* kgb   = (unsigned short*)(wsb + 50*MB);    //  4 MB
    unsigned short* wa    = (unsigned short*)(wsb + 56*MB);    // 40 MB weight arena
    unsigned short* bQKV  = (unsigned short*)(wsb + 96*MB);    // 48 MB
    unsigned short* bKV   = (unsigned short*)(wsb + 144*MB);   //  8 MB
    unsigned short* hb    = (unsigned short*)(wsb + 96*MB);    // 64 MB, overlays bQKV/bKV

    CvtArgs ca;
    int u = 0;
    auto addu = [&](const float* src, int melems, unsigned short* dst) {
        for (int i = 0; i < melems; ++i) {
            ca.src[u] = src + (size_t)i * MELEM;
            ca.dst[u] = dst + (size_t)i * MELEM;
            ++u;
        }
    };
    addu(qw + 0*WSTEP, 1, wa + 0*MELEM);
    addu(kw + 0*WSTEP, 1, wa + 1*MELEM);
    addu(vw + 0*WSTEP, 1, wa + 2*MELEM);
    addu(qw + 1*WSTEP, 1, wa + 3*MELEM);
    addu(kw + 1*WSTEP, 1, wa + 4*MELEM);
    addu(vw + 1*WSTEP, 1, wa + 5*MELEM);
    addu(qw + 2*WSTEP, 1, wa + 6*MELEM);
    addu(kw + 2*WSTEP, 1, wa + 7*MELEM);
    addu(vw + 2*WSTEP, 1, wa + 8*MELEM);
    addu(ow + 0*WSTEP, 1, wa + 9*MELEM);
    addu(ow + 1*WSTEP, 1, wa + 10*MELEM);
    addu(ow + 2*WSTEP, 1, wa + 11*MELEM);
    addu(w1, 4, wa + 12*MELEM);
    addu(w2, 4, wa + 16*MELEM);
    addu(img,  8, xb);
    addu(ques, 1, quesb);
    addu(kg,   2, kgb);

    dim3 blk(256);
    cvt_units<<<dim3(512, u), blk, 0, stream>>>(ca);

    auto gemm = [&](const unsigned short* A, const unsigned short* W,
                    const float* ba, const float* bb_, const float* bc, const float* bd,
                    unsigned short* C, int M, int N, int K, int relu) {
        dim3 grid(M / 128, N / 128);
        if (relu) gemm_mfma<1><<<grid, blk, 0, stream>>>(
            (const bf16_t*)A, (const bf16_t*)W, ba, bb_, bc, bd, C, M, N, K);
        else      gemm_mfma<0><<<grid, blk, 0, stream>>>(
            (const bf16_t*)A, (const bf16_t*)W, ba, bb_, bc, bd, C, M, N, K);
    };

    const unsigned short* Akv[3] = {xb, quesb, kgb};
    const int Mkv[3] = {NX, B * 64, B * 128};
    const int Lk[3]  = {512, 64, 128};

    dim3 ablk(512);
    dim3 agrid(NHEADS, B);

    for (int t = 0; t < 3; ++t) {
        if (t == 0) {
            gemm(xb, wa + 0*MELEM, qb + 0, kb + 0, vb + 0, vb + 0,
                 bQKV, NX, 3072, 1024, 0);
            attn_mfma<0><<<agrid, ablk, 0, stream>>>(
                (const bf16_t*)bQKV, (const bf16_t*)bQKV + 1024, (const bf16_t*)bQKV + 2048,
                3072, 3072, nullptr, bOb, Lk[t]);
        } else {
            gemm(xb, wa + (t == 1 ? 3 : 6)*MELEM,
                 qb + t*1024, qb + t*1024, qb + t*1024, qb + t*1024,
                 bQKV, NX, 1024, 1024, 0);
            gemm(Akv[t], wa + (t == 1 ? 4 : 7)*MELEM,
                 kb + t*1024, vb + t*1024, vb + t*1024, vb + t*1024,
                 bKV, Mkv[t], 2048, 1024, 0);
            attn_mfma<1><<<agrid, ablk, 0, stream>>>(
                (const bf16_t*)bQKV, (const bf16_t*)bKV, (const bf16_t*)bKV + 1024,
                1024, 2048, (t == 1 ? qmask : kmask), bOb, Lk[t]);
        }
        gemm(bOb, wa + (9 + t)*MELEM,
             ob + t*1024, ob + t*1024, ob + t*1024, ob + t*1024,
             bM, NX, 1024, 1024, 0);
        ln_res_b<0,1><<<NX, blk, 0, stream>>>(xb, bM, lng + t*1024, lnb + t*1024, xb, nullptr);
    }

    // FFN
    gemm(xb, wa + 12*MELEM, b1, b1 + 1024, b1 + 2048, b1 + 3072, hb, NX, FFD, 1024, 1);
    gemm(hb, wa + 16*MELEM, b2, b2, b2, b2, bM, NX, 1024, 4096, 0);
    ln_res_b<1,0><<<NX, blk, 0, stream>>>(xb, bM, lng + 3*1024, lnb + 3*1024, nullptr, out);
}